// Round 1
// baseline (9667.045 us; speedup 1.0000x reference)
//
#include <hip/hip_runtime.h>
#include <cstdint>
#include <cstddef>

#define B_ 8
#define T_ 1024
#define D_ 512
#define H_ 8
#define DH_ 64
#define DEPTH_ 8
#define FF_ 2048
#define NH_ 8
#define BS_ 64
#define NB_ 16
#define NC_ 128
#define BH_ 64
#define ROWS_ 8192   // B*T

// ---------------------------------------------------------------- utilities
__device__ __forceinline__ float wave_sum(float v) {
#pragma unroll
  for (int o = 1; o < 64; o <<= 1) v += __shfl_xor(v, o);
  return v;
}

__device__ __forceinline__ float gelu_f(float u) {
  float c = u + 0.044715f * u * u * u;
  float t = tanhf(0.7978845608028654f * c);
  return 0.5f * u * (1.0f + t);
}

// ---------------------------------------------------------------- embedding
__global__ __launch_bounds__(128) void k_embed(const int* __restrict__ ids,
                                               const float* __restrict__ te,
                                               const float* __restrict__ pe,
                                               float* __restrict__ x1,
                                               float* __restrict__ x2) {
  int bt = blockIdx.x;
  int t = bt & (T_ - 1);
  int d = threadIdx.x * 4;
  int id = ids[bt];
  float4 v = *(const float4*)(te + (size_t)id * D_ + d);
  float4 p = *(const float4*)(pe + (size_t)t * D_ + d);
  v.x += p.x; v.y += p.y; v.z += p.z; v.w += p.w;
  *(float4*)(x1 + (size_t)bt * D_ + d) = v;
  *(float4*)(x2 + (size_t)bt * D_ + d) = v;
}

// ---------------------------------------------------------------- layernorm
// one wave per row; if xb != null, input = 0.5*(x + xb)
__global__ __launch_bounds__(256) void k_ln(const float* __restrict__ x,
                                            const float* __restrict__ xb,
                                            const float* __restrict__ g,
                                            const float* __restrict__ bb,
                                            float* __restrict__ y) {
  int w = threadIdx.x >> 6, lane = threadIdx.x & 63;
  size_t row = (size_t)blockIdx.x * 4 + w;
  const float* xr = x + row * D_ + lane * 8;
  float v[8];
  *(float4*)(v)     = *(const float4*)(xr);
  *(float4*)(v + 4) = *(const float4*)(xr + 4);
  if (xb) {
    const float* x2r = xb + row * D_ + lane * 8;
    float u[8];
    *(float4*)(u)     = *(const float4*)(x2r);
    *(float4*)(u + 4) = *(const float4*)(x2r + 4);
#pragma unroll
    for (int i = 0; i < 8; ++i) v[i] = 0.5f * (v[i] + u[i]);
  }
  float s = 0.f;
#pragma unroll
  for (int i = 0; i < 8; ++i) s += v[i];
  s = wave_sum(s);
  float m = s * (1.0f / D_);
  float q = 0.f;
#pragma unroll
  for (int i = 0; i < 8; ++i) { float d = v[i] - m; q += d * d; }
  q = wave_sum(q);
  float inv = 1.0f / sqrtf(q * (1.0f / D_) + 1e-5f);
  float gg[8], bv[8];
  *(float4*)(gg)     = *(const float4*)(g + lane * 8);
  *(float4*)(gg + 4) = *(const float4*)(g + lane * 8 + 4);
  *(float4*)(bv)     = *(const float4*)(bb + lane * 8);
  *(float4*)(bv + 4) = *(const float4*)(bb + lane * 8 + 4);
  float o[8];
#pragma unroll
  for (int i = 0; i < 8; ++i) o[i] = (v[i] - m) * inv * gg[i] + bv[i];
  float* yr = y + row * D_ + lane * 8;
  *(float4*)(yr)     = *(float4*)(o);
  *(float4*)(yr + 4) = *(float4*)(o + 4);
}

// ---------------------------------------------------------------- SGEMM
// C[M,N] (M multiple of 128, N multiple of 128, K multiple of 32)
// EPI: 0 C=AB ; 1 C+=AB ; 2 C=gelu(AB+bias) ; 3 C+=AB+bias
template <int EPI>
__global__ __launch_bounds__(256) void k_sgemm(const float* __restrict__ A,
                                               const float* __restrict__ Bm,
                                               const float* __restrict__ bias,
                                               float* __restrict__ C,
                                               int N, int K) {
  __shared__ float As[32][128];
  __shared__ float Bs[32][128];
  const int bn0 = blockIdx.x * 128;
  const int bm0 = blockIdx.y * 128;
  const int tid = threadIdx.x;
  const int w = tid >> 6, lane = tid & 63;
  const int wy = w >> 1, wx = w & 1;
  const int ly = lane >> 3, lx = lane & 7;
  const int rm = wy * 64 + ly * 8;
  const int cn = wx * 64 + lx * 8;
  float acc[8][8] = {};

  for (int k0 = 0; k0 < K; k0 += 32) {
#pragma unroll
    for (int ld = 0; ld < 4; ++ld) {
      int f = tid + ld * 256;            // 0..1023
      int ar = f >> 3;                   // 0..127
      int ac = (f & 7) << 2;             // 0..28
      float4 av = *(const float4*)(A + (size_t)(bm0 + ar) * K + k0 + ac);
      As[ac + 0][ar] = av.x; As[ac + 1][ar] = av.y;
      As[ac + 2][ar] = av.z; As[ac + 3][ar] = av.w;
      int br = f >> 5;                   // 0..31
      int bc = (f & 31) << 2;            // 0..124
      *(float4*)(&Bs[br][bc]) = *(const float4*)(Bm + (size_t)(k0 + br) * N + bn0 + bc);
    }
    __syncthreads();
#pragma unroll
    for (int kk = 0; kk < 32; ++kk) {
      float a[8], b[8];
      *(float4*)(a)     = *(const float4*)(&As[kk][rm]);
      *(float4*)(a + 4) = *(const float4*)(&As[kk][rm + 4]);
      *(float4*)(b)     = *(const float4*)(&Bs[kk][cn]);
      *(float4*)(b + 4) = *(const float4*)(&Bs[kk][cn + 4]);
#pragma unroll
      for (int i = 0; i < 8; ++i)
#pragma unroll
        for (int j = 0; j < 8; ++j) acc[i][j] += a[i] * b[j];
    }
    __syncthreads();
  }

#pragma unroll
  for (int i = 0; i < 8; ++i) {
    float* crow = C + (size_t)(bm0 + rm + i) * N + bn0 + cn;
#pragma unroll
    for (int j0 = 0; j0 < 8; j0 += 4) {
      float4 r = make_float4(acc[i][j0], acc[i][j0 + 1], acc[i][j0 + 2], acc[i][j0 + 3]);
      if (EPI == 2 || EPI == 3) {
        float4 bi = *(const float4*)(bias + bn0 + cn + j0);
        r.x += bi.x; r.y += bi.y; r.z += bi.z; r.w += bi.w;
      }
      if (EPI == 2) {
        r.x = gelu_f(r.x); r.y = gelu_f(r.y); r.z = gelu_f(r.z); r.w = gelu_f(r.w);
      }
      if (EPI == 1 || EPI == 3) {
        float4 c0 = *(const float4*)(crow + j0);
        r.x += c0.x; r.y += c0.y; r.z += c0.z; r.w += c0.w;
      }
      *(float4*)(crow + j0) = r;
    }
  }
}

// ---------------------------------------------------------------- LSH bucket ids
// grid 512 = b(8) x h(8) x tchunk(8); block 128; one row (b,h,t) per thread
__global__ __launch_bounds__(128) void k_bucket(const float* __restrict__ qk,
                                                const float* __restrict__ rotL,
                                                unsigned char* __restrict__ bkt) {
  int blk = blockIdx.x;
  int tc = blk & 7, h = (blk >> 3) & 7, b = blk >> 6;
  int t0 = tc << 7;
  __shared__ float qs[128][65];
  __shared__ float rs[4096];   // [d][r*8+j]
  int tid = threadIdx.x;
  for (int f = tid; f < 4096; f += 128) rs[f] = rotL[f];
  const float* base = qk + ((size_t)(b * T_ + t0)) * D_ + h * DH_;
  for (int f = tid; f < 2048; f += 128) {
    int rw = f >> 4, c4 = (f & 15) << 2;
    float4 v = *(const float4*)(base + (size_t)rw * D_ + c4);
    qs[rw][c4] = v.x; qs[rw][c4 + 1] = v.y; qs[rw][c4 + 2] = v.z; qs[rw][c4 + 3] = v.w;
  }
  __syncthreads();
  float s[64];
#pragma unroll
  for (int jr = 0; jr < 64; ++jr) s[jr] = 0.f;
  for (int d = 0; d < 64; ++d) {
    float q = qs[tid][d];
    const float* rp = rs + d * 64;
#pragma unroll
    for (int j4 = 0; j4 < 16; ++j4) {
      float4 rv = *(const float4*)(rp + j4 * 4);
      s[j4 * 4 + 0] += q * rv.x; s[j4 * 4 + 1] += q * rv.y;
      s[j4 * 4 + 2] += q * rv.z; s[j4 * 4 + 3] += q * rv.w;
    }
  }
  int bh = b * H_ + h;
#pragma unroll
  for (int r = 0; r < 8; ++r) {
    float best = s[r * 8];
    int bi = 0;
#pragma unroll
    for (int idx = 1; idx < 16; ++idx) {
      float v = (idx < 8) ? s[r * 8 + idx] : -s[r * 8 + idx - 8];
      if (v > best) { best = v; bi = idx; }
    }
    bkt[((size_t)(bh * NH_ + r)) * T_ + t0 + tid] = (unsigned char)bi;
  }
}

// ---------------------------------------------------------------- stable counting sort
// grid 512 = (bh<<3)|r ; block 1024 ; sorts 1024 positions by 4-bit bucket, stable by t
__global__ __launch_bounds__(1024) void k_sort(const unsigned char* __restrict__ bkt,
                                               int* __restrict__ st) {
  int r = blockIdx.x & 7, bh = blockIdx.x >> 3;
  int t = threadIdx.x;
  int bk = bkt[((size_t)(bh * NH_ + r)) * T_ + t];
  int w = t >> 6, lane = t & 63;
  __shared__ int cnt[16][16];
  __shared__ int off[16][16];
  __shared__ int tot[16];
  __shared__ int stt[16];
  unsigned long long below = (1ULL << lane) - 1ULL;
  int myrank = 0;
#pragma unroll
  for (int bb = 0; bb < 16; ++bb) {
    unsigned long long m = __ballot(bk == bb);
    if (bk == bb) myrank = __popcll(m & below);
    if (lane == 0) cnt[w][bb] = __popcll(m);
  }
  __syncthreads();
  if (t < 16) {
    int run = 0;
    for (int ww = 0; ww < 16; ++ww) { off[ww][t] = run; run += cnt[ww][t]; }
    tot[t] = run;
  }
  __syncthreads();
  if (t == 0) {
    int run = 0;
    for (int bb = 0; bb < 16; ++bb) { stt[bb] = run; run += tot[bb]; }
  }
  __syncthreads();
  int pos = stt[bk] + off[w][bk] + myrank;
  st[((size_t)(bh * NH_ + r)) * T_ + pos] = t;
}

// ---------------------------------------------------------------- chunked attention
// grid (c=128, bh=64); block 256; 64 queries x 128 keys (chunk + prev chunk)
__global__ __launch_bounds__(256) void k_attn(const float* __restrict__ qk,
                                              const float* __restrict__ vv,
                                              const int* __restrict__ st,
                                              float* __restrict__ ob,
                                              float* __restrict__ lgb) {
  int c = blockIdx.x, bh = blockIdx.y;
  int b = bh >> 3, h = bh & 7;
  int r = c >> 4;
  int pc = (c + NC_ - 1) & (NC_ - 1);
  __shared__ float KQ[128][68];
  __shared__ float Vs[128][68];
  __shared__ float inv[128];
  __shared__ int pos[128];
  int tid = threadIdx.x;
  if (tid < 128) {
    int j = tid;
    int sc = (j < 64) ? c : pc;
    int slot = ((sc & 15) << 6) + (j & 63);
    pos[j] = st[((size_t)(bh * NH_ + (sc >> 4))) * T_ + slot];
  }
  __syncthreads();
  const float* qkbase = qk + ((size_t)b * T_) * D_ + h * DH_;
  const float* vbase  = vv + ((size_t)b * T_) * D_ + h * DH_;
#pragma unroll
  for (int ld = 0; ld < 8; ++ld) {
    int f = ld * 256 + tid;
    int rw = f >> 4, c4 = (f & 15) << 2;
    int p0 = pos[rw];
    *(float4*)(&KQ[rw][c4]) = *(const float4*)(qkbase + (size_t)p0 * D_ + c4);
    *(float4*)(&Vs[rw][c4]) = *(const float4*)(vbase + (size_t)p0 * D_ + c4);
  }
  __syncthreads();
  if (tid < 128) {
    float ss = 0.f;
#pragma unroll
    for (int d4 = 0; d4 < 64; d4 += 4) {
      float4 v = *(const float4*)(&KQ[tid][d4]);
      ss += v.x * v.x + v.y * v.y + v.z * v.z + v.w * v.w;
    }
    inv[tid] = 1.0f / (sqrtf(ss) + 1e-8f);
  }
  __syncthreads();

  int i = tid >> 2, p = tid & 3;
  int mypos = pos[i];
  float dj[32];
#pragma unroll
  for (int jj = 0; jj < 32; ++jj) dj[jj] = 0.f;
#pragma unroll
  for (int d0 = 0; d0 < 64; d0 += 16) {
    float qreg[16];
    *(float4*)(qreg)      = *(const float4*)(&KQ[i][d0]);
    *(float4*)(qreg + 4)  = *(const float4*)(&KQ[i][d0 + 4]);
    *(float4*)(qreg + 8)  = *(const float4*)(&KQ[i][d0 + 8]);
    *(float4*)(qreg + 12) = *(const float4*)(&KQ[i][d0 + 12]);
#pragma unroll
    for (int jj = 0; jj < 32; ++jj) {
      int j = (jj << 2) + p;
      float kreg[16];
      *(float4*)(kreg)      = *(const float4*)(&KQ[j][d0]);
      *(float4*)(kreg + 4)  = *(const float4*)(&KQ[j][d0 + 4]);
      *(float4*)(kreg + 8)  = *(const float4*)(&KQ[j][d0 + 8]);
      *(float4*)(kreg + 12) = *(const float4*)(&KQ[j][d0 + 12]);
      float t0 = 0.f;
#pragma unroll
      for (int dd = 0; dd < 16; ++dd) t0 += qreg[dd] * kreg[dd];
      dj[jj] += t0;
    }
  }
  const float scale = 0.125f;
  float mloc = -3.0e38f;
#pragma unroll
  for (int jj = 0; jj < 32; ++jj) {
    int j = (jj << 2) + p;
    float dv = dj[jj] * inv[j] * scale;
    dv = (pos[j] == mypos) ? -5.0e4f : dv;
    dj[jj] = dv;
    mloc = fmaxf(mloc, dv);
  }
  mloc = fmaxf(mloc, __shfl_xor(mloc, 1));
  mloc = fmaxf(mloc, __shfl_xor(mloc, 2));
  float ls = 0.f;
#pragma unroll
  for (int jj = 0; jj < 32; ++jj) {
    float e = expf(dj[jj] - mloc);
    dj[jj] = e;
    ls += e;
  }
  ls += __shfl_xor(ls, 1);
  ls += __shfl_xor(ls, 2);
  float logit = mloc + logf(ls);
  float invl = 1.0f / ls;
  float acc[64];
#pragma unroll
  for (int d = 0; d < 64; ++d) acc[d] = 0.f;
#pragma unroll
  for (int jj = 0; jj < 32; ++jj) {
    int j = (jj << 2) + p;
    float wgt = dj[jj] * invl;
#pragma unroll
    for (int d4 = 0; d4 < 64; d4 += 4) {
      float4 v = *(const float4*)(&Vs[j][d4]);
      acc[d4 + 0] += wgt * v.x; acc[d4 + 1] += wgt * v.y;
      acc[d4 + 2] += wgt * v.z; acc[d4 + 3] += wgt * v.w;
    }
  }
#pragma unroll
  for (int d = 0; d < 64; ++d) {
    acc[d] += __shfl_xor(acc[d], 1);
    acc[d] += __shfl_xor(acc[d], 2);
  }
  float* orow = ob + (((size_t)(bh * NH_ + r)) * T_ + mypos) * DH_;
#pragma unroll
  for (int dd = 0; dd < 16; dd += 4) {
    int d = (p << 4) + dd;
    *(float4*)(orow + d) = make_float4(acc[d], acc[d + 1], acc[d + 2], acc[d + 3]);
  }
  if (p == 0) lgb[((size_t)(bh * NH_ + r)) * T_ + mypos] = logit;
}

// ---------------------------------------------------------------- round combine
// block 256 = 4 x (64 lanes = DH); softmax over 8 rounds of logsumexp
__global__ __launch_bounds__(256) void k_combine(const float* __restrict__ ob,
                                                 const float* __restrict__ lgb,
                                                 float* __restrict__ attn) {
  int g = threadIdx.x >> 6, lane = threadIdx.x & 63;
  int idx = blockIdx.x * 4 + g;
  int bh = idx >> 10, t = idx & (T_ - 1);
  int b = bh >> 3, h = bh & 7;
  float lg[8];
  float m = -3.0e38f;
#pragma unroll
  for (int r = 0; r < 8; ++r) {
    lg[r] = lgb[((size_t)(bh * NH_ + r)) * T_ + t];
    m = fmaxf(m, lg[r]);
  }
  float s = 0.f;
#pragma unroll
  for (int r = 0; r < 8; ++r) { lg[r] = expf(lg[r] - m); s += lg[r]; }
  float invs = 1.0f / s;
  float o = 0.f;
#pragma unroll
  for (int r = 0; r < 8; ++r)
    o += lg[r] * invs * ob[(((size_t)(bh * NH_ + r)) * T_ + t) * DH_ + lane];
  attn[((size_t)(b * T_ + t)) * D_ + h * DH_ + lane] = o;
}

// ---------------------------------------------------------------- final reduction
__global__ void k_zero(float* __restrict__ p, int n) {
  int i = blockIdx.x * blockDim.x + threadIdx.x;
  if (i < n) p[i] = 0.f;
}

__global__ __launch_bounds__(256) void k_colsum(const float* __restrict__ xn,
                                                float* __restrict__ mean) {
  int b = blockIdx.x, dc = blockIdx.y, tc = blockIdx.z;
  int d = dc * 256 + threadIdx.x;
  float s = 0.f;
  for (int tt = 0; tt < 64; ++tt) {
    int t = tc * 64 + tt;
    s += xn[((size_t)(b * T_ + t)) * D_ + d];
  }
  atomicAdd(&mean[b * D_ + d], s);
}

__global__ __launch_bounds__(512) void k_fc(const float* __restrict__ mean,
                                            const float* __restrict__ Wfc,
                                            float* __restrict__ out) {
  int b = blockIdx.x, n = threadIdx.x;
  __shared__ float ms[512];
  ms[n] = mean[b * D_ + n] * (1.0f / 1024.0f);
  __syncthreads();
  float acc = 0.f;
  for (int d = 0; d < 512; ++d) acc += ms[d] * Wfc[(size_t)d * D_ + n];
  out[b * D_ + n] = acc;
}

// ---------------------------------------------------------------- launcher
extern "C" void kernel_launch(void* const* d_in, const int* in_sizes, int n_in,
                              void* d_out, int out_size, void* d_ws, size_t ws_size,
                              hipStream_t stream) {
  (void)in_sizes; (void)n_in; (void)out_size; (void)ws_size;
  const int*   ids  = (const int*)d_in[0];
  const float* te   = (const float*)d_in[1];
  const float* pe   = (const float*)d_in[2];
  const float* lag  = (const float*)d_in[3];   // ln_attn_g [8,512]
  const float* lab  = (const float*)d_in[4];   // ln_attn_b
  const float* Wqk  = (const float*)d_in[5];   // [8,512,512]
  const float* Wv   = (const float*)d_in[6];
  const float* Wo   = (const float*)d_in[7];
  const float* lfg  = (const float*)d_in[8];   // ln_ff_g
  const float* lfb  = (const float*)d_in[9];   // ln_ff_b
  const float* W1   = (const float*)d_in[10];  // [8,512,2048]
  const float* b1   = (const float*)d_in[11];  // [8,2048]
  const float* W2   = (const float*)d_in[12];  // [8,2048,512]
  const float* b2   = (const float*)d_in[13];  // [8,512]
  const float* lnfg = (const float*)d_in[14];  // ln_f_g [512]
  const float* lnfb = (const float*)d_in[15];
  const float* Wfc  = (const float*)d_in[16];  // [512,512]
  const float* rot  = (const float*)d_in[17];  // [8,64,8,8]

  char* ws = (char*)d_ws;
  size_t off = 0;
  auto carve = [&](size_t bytes) -> void* {
    void* p = ws + off;
    off += (bytes + 255) & ~(size_t)255;
    return p;
  };
  float* x1    = (float*)carve((size_t)ROWS_ * D_ * 4);
  float* x2    = (float*)carve((size_t)ROWS_ * D_ * 4);
  float* xn    = (float*)carve((size_t)ROWS_ * D_ * 4);
  float* qkb   = (float*)carve((size_t)ROWS_ * D_ * 4);
  float* vvb   = (float*)carve((size_t)ROWS_ * D_ * 4);
  float* attnb = (float*)carve((size_t)ROWS_ * D_ * 4);
  float* ob    = (float*)carve((size_t)BH_ * NH_ * T_ * DH_ * 4);  // 134 MB; also FF hidden
  float* hid   = ob;  // alias: ob dead after combine, hid needs 64 MB <= 134 MB
  unsigned char* bkt = (unsigned char*)carve((size_t)BH_ * NH_ * T_);
  int*   stb   = (int*)carve((size_t)BH_ * NH_ * T_ * 4);
  float* lgb   = (float*)carve((size_t)BH_ * NH_ * T_ * 4);
  float* meanb = (float*)carve((size_t)B_ * D_ * 4);

  k_embed<<<ROWS_, 128, 0, stream>>>(ids, te, pe, x1, x2);

  for (int l = 0; l < DEPTH_; ++l) {
    const float* wqk = Wqk + (size_t)l * D_ * D_;
    const float* wv  = Wv  + (size_t)l * D_ * D_;
    const float* wo  = Wo  + (size_t)l * D_ * D_;
    const float* w1  = W1  + (size_t)l * D_ * FF_;
    const float* w2  = W2  + (size_t)l * FF_ * D_;

    k_ln<<<ROWS_ / 4, 256, 0, stream>>>(x2, nullptr, lag + l * D_, lab + l * D_, xn);
    k_sgemm<0><<<dim3(D_ / 128, ROWS_ / 128), 256, 0, stream>>>(xn, wqk, nullptr, qkb, D_, D_);
    k_sgemm<0><<<dim3(D_ / 128, ROWS_ / 128), 256, 0, stream>>>(xn, wv, nullptr, vvb, D_, D_);
    k_bucket<<<512, 128, 0, stream>>>(qkb, rot + (size_t)l * 4096, bkt);
    k_sort<<<512, 1024, 0, stream>>>(bkt, stb);
    k_attn<<<dim3(NC_, BH_), 256, 0, stream>>>(qkb, vvb, stb, ob, lgb);
    k_combine<<<BH_ * T_ / 4, 256, 0, stream>>>(ob, lgb, attnb);
    k_sgemm<1><<<dim3(D_ / 128, ROWS_ / 128), 256, 0, stream>>>(attnb, wo, nullptr, x1, D_, D_);

    k_ln<<<ROWS_ / 4, 256, 0, stream>>>(x1, nullptr, lfg + l * D_, lfb + l * D_, xn);
    k_sgemm<2><<<dim3(FF_ / 128, ROWS_ / 128), 256, 0, stream>>>(xn, w1, b1 + l * FF_, hid, FF_, D_);
    k_sgemm<3><<<dim3(D_ / 128, ROWS_ / 128), 256, 0, stream>>>(hid, w2, b2 + l * D_, x2, D_, FF_);
  }

  k_ln<<<ROWS_ / 4, 256, 0, stream>>>(x1, x2, lnfg, lnfb, xn);
  k_zero<<<16, 256, 0, stream>>>(meanb, B_ * D_);
  k_colsum<<<dim3(B_, 2, 16), 256, 0, stream>>>(xn, meanb);
  k_fc<<<B_, 512, 0, stream>>>(meanb, Wfc, (float*)d_out);
}

// Round 3
// 6020.971 us; speedup vs baseline: 1.6056x; 1.6056x over previous
//
#include <hip/hip_runtime.h>
#include <hip/hip_bf16.h>
#include <cstdint>
#include <cstddef>

#define B_ 8
#define T_ 1024
#define D_ 512
#define H_ 8
#define DH_ 64
#define DEPTH_ 8
#define FF_ 2048
#define NH_ 8
#define BS_ 64
#define NB_ 16
#define NC_ 128
#define BH_ 64
#define ROWS_ 8192   // B*T

typedef __attribute__((ext_vector_type(8))) short bf16x8;
typedef __attribute__((ext_vector_type(4))) float f32x4;

typedef __attribute__((address_space(1))) const unsigned int g_u32;
typedef __attribute__((address_space(3))) unsigned int l_u32;
__device__ __forceinline__ void gload16(const void* g, void* l) {
  __builtin_amdgcn_global_load_lds((g_u32*)g, (l_u32*)l, 16, 0, 0);
}

// ---------------------------------------------------------------- utilities
__device__ __forceinline__ float wave_sum(float v) {
#pragma unroll
  for (int o = 1; o < 64; o <<= 1) v += __shfl_xor(v, o);
  return v;
}

__device__ __forceinline__ float gelu_f(float u) {
  float c = u + 0.044715f * u * u * u;
  float t = tanhf(0.7978845608028654f * c);
  return 0.5f * u * (1.0f + t);
}

// ---------------------------------------------------------------- embedding
__global__ __launch_bounds__(128) void k_embed(const int* __restrict__ ids,
                                               const float* __restrict__ te,
                                               const float* __restrict__ pe,
                                               float* __restrict__ x1,
                                               float* __restrict__ x2) {
  int bt = blockIdx.x;
  int t = bt & (T_ - 1);
  int d = threadIdx.x * 4;
  int id = ids[bt];
  float4 v = *(const float4*)(te + (size_t)id * D_ + d);
  float4 p = *(const float4*)(pe + (size_t)t * D_ + d);
  v.x += p.x; v.y += p.y; v.z += p.z; v.w += p.w;
  *(float4*)(x1 + (size_t)bt * D_ + d) = v;
  *(float4*)(x2 + (size_t)bt * D_ + d) = v;
}

// ---------------------------------------------------------------- weight transpose + bf16
// in: W [K][N] fp32 ; out: WT [N][K] bf16 ; blockIdx.z = layer
__global__ __launch_bounds__(256) void k_wt(const float* __restrict__ W,
                                            __hip_bfloat16* __restrict__ WT,
                                            int K, int N) {
  const float* Wl = W + (size_t)blockIdx.z * K * N;
  __hip_bfloat16* WTl = WT + (size_t)blockIdx.z * K * N;
  __shared__ float tile[32][33];
  int n0 = blockIdx.x * 32, k0 = blockIdx.y * 32;
  int tx = threadIdx.x & 31, ty = threadIdx.x >> 5;  // 32 x 8
#pragma unroll
  for (int i = 0; i < 32; i += 8)
    tile[ty + i][tx] = Wl[(size_t)(k0 + ty + i) * N + n0 + tx];
  __syncthreads();
#pragma unroll
  for (int i = 0; i < 32; i += 8)
    WTl[(size_t)(n0 + ty + i) * K + k0 + tx] = __float2bfloat16(tile[tx][ty + i]);
}

// ---------------------------------------------------------------- layernorm
// one wave per row; if xb != null, input = 0.5*(x + xb); y (fp32) and yb (bf16) nullable
__global__ __launch_bounds__(256) void k_ln(const float* __restrict__ x,
                                            const float* __restrict__ xb,
                                            const float* __restrict__ g,
                                            const float* __restrict__ bb,
                                            float* __restrict__ y,
                                            __hip_bfloat16* __restrict__ yb) {
  int w = threadIdx.x >> 6, lane = threadIdx.x & 63;
  size_t row = (size_t)blockIdx.x * 4 + w;
  const float* xr = x + row * D_ + lane * 8;
  float v[8];
  *(float4*)(v)     = *(const float4*)(xr);
  *(float4*)(v + 4) = *(const float4*)(xr + 4);
  if (xb) {
    const float* x2r = xb + row * D_ + lane * 8;
    float u[8];
    *(float4*)(u)     = *(const float4*)(x2r);
    *(float4*)(u + 4) = *(const float4*)(x2r + 4);
#pragma unroll
    for (int i = 0; i < 8; ++i) v[i] = 0.5f * (v[i] + u[i]);
  }
  float s = 0.f;
#pragma unroll
  for (int i = 0; i < 8; ++i) s += v[i];
  s = wave_sum(s);
  float m = s * (1.0f / D_);
  float q = 0.f;
#pragma unroll
  for (int i = 0; i < 8; ++i) { float d = v[i] - m; q += d * d; }
  q = wave_sum(q);
  float inv = 1.0f / sqrtf(q * (1.0f / D_) + 1e-5f);
  float gg[8], bv[8];
  *(float4*)(gg)     = *(const float4*)(g + lane * 8);
  *(float4*)(gg + 4) = *(const float4*)(g + lane * 8 + 4);
  *(float4*)(bv)     = *(const float4*)(bb + lane * 8);
  *(float4*)(bv + 4) = *(const float4*)(bb + lane * 8 + 4);
  float o[8];
#pragma unroll
  for (int i = 0; i < 8; ++i) o[i] = (v[i] - m) * inv * gg[i] + bv[i];
  if (y) {
    float* yr = y + row * D_ + lane * 8;
    *(float4*)(yr)     = *(float4*)(o);
    *(float4*)(yr + 4) = *(float4*)(o + 4);
  }
  if (yb) {
    __hip_bfloat16 o16[8];
#pragma unroll
    for (int i = 0; i < 8; ++i) o16[i] = __float2bfloat16(o[i]);
    *(uint4*)(yb + row * D_ + lane * 8) = *(uint4*)o16;
  }
}

// ---------------------------------------------------------------- fp32 SGEMM (qk projection only)
__global__ __launch_bounds__(256) void k_sgemm(const float* __restrict__ A,
                                               const float* __restrict__ Bm,
                                               float* __restrict__ C,
                                               int N, int K) {
  __shared__ float As[32][128];
  __shared__ float Bs[32][128];
  const int bn0 = blockIdx.x * 128;
  const int bm0 = blockIdx.y * 128;
  const int tid = threadIdx.x;
  const int w = tid >> 6, lane = tid & 63;
  const int wy = w >> 1, wx = w & 1;
  const int ly = lane >> 3, lx = lane & 7;
  const int rm = wy * 64 + ly * 8;
  const int cn = wx * 64 + lx * 8;
  float acc[8][8] = {};

  for (int k0 = 0; k0 < K; k0 += 32) {
#pragma unroll
    for (int ld = 0; ld < 4; ++ld) {
      int f = tid + ld * 256;
      int ar = f >> 3;
      int ac = (f & 7) << 2;
      float4 av = *(const float4*)(A + (size_t)(bm0 + ar) * K + k0 + ac);
      As[ac + 0][ar] = av.x; As[ac + 1][ar] = av.y;
      As[ac + 2][ar] = av.z; As[ac + 3][ar] = av.w;
      int br = f >> 5;
      int bc = (f & 31) << 2;
      *(float4*)(&Bs[br][bc]) = *(const float4*)(Bm + (size_t)(k0 + br) * N + bn0 + bc);
    }
    __syncthreads();
#pragma unroll
    for (int kk = 0; kk < 32; ++kk) {
      float a[8], b[8];
      *(float4*)(a)     = *(const float4*)(&As[kk][rm]);
      *(float4*)(a + 4) = *(const float4*)(&As[kk][rm + 4]);
      *(float4*)(b)     = *(const float4*)(&Bs[kk][cn]);
      *(float4*)(b + 4) = *(const float4*)(&Bs[kk][cn + 4]);
#pragma unroll
      for (int i = 0; i < 8; ++i)
#pragma unroll
        for (int j = 0; j < 8; ++j) acc[i][j] += a[i] * b[j];
    }
    __syncthreads();
  }
#pragma unroll
  for (int i = 0; i < 8; ++i) {
    float* crow = C + (size_t)(bm0 + rm + i) * N + bn0 + cn;
#pragma unroll
    for (int j0 = 0; j0 < 8; j0 += 4)
      *(float4*)(crow + j0) = make_float4(acc[i][j0], acc[i][j0 + 1], acc[i][j0 + 2], acc[i][j0 + 3]);
  }
}

// ---------------------------------------------------------------- bf16 MFMA GEMM
// C[M,N] = A[M,K](bf16) x BT[N,K](bf16); BM=BN=128, BK=32, 256 thr (2x2 waves, 64x64/wave)
// EPI: 0 C(f32)=AB ; 1 C(f32)+=AB ; 2 C(bf16)=gelu(AB+bias) ; 3 C(f32)+=AB+bias
template <int EPI>
__global__ __launch_bounds__(256) void k_bgemm(const __hip_bfloat16* __restrict__ A,
                                               const __hip_bfloat16* __restrict__ BT,
                                               const float* __restrict__ bias,
                                               void* __restrict__ Cv,
                                               int N, int K) {
  __shared__ __align__(16) __hip_bfloat16 As[128 * 32];
  __shared__ __align__(16) __hip_bfloat16 Bs[128 * 32];
  const int bn0 = blockIdx.x * 128;
  const int bm0 = blockIdx.y * 128;
  const int tid = threadIdx.x;
  const int w = tid >> 6, lane = tid & 63;
  const int wy = w >> 1, wx = w & 1;
  const int g = lane >> 4, lr = lane & 15;
  f32x4 acc[4][4] = {};

  const __hip_bfloat16* Abase = A + (size_t)bm0 * K;
  const __hip_bfloat16* Bbase = BT + (size_t)bn0 * K;

  for (int k0 = 0; k0 < K; k0 += 32) {
    // stage 128x32 bf16 tiles; LDS linear (row-major, 4 chunks of 8 bf16 per row),
    // source-permuted so reads use XOR swizzle (pos = g ^ ((row>>1)&3)) -> 2-way banks
#pragma unroll
    for (int it = 0; it < 2; ++it) {
      int f = it * 256 + w * 64 + lane;
      int row = f >> 2;
      int kc = ((f & 3) ^ ((row >> 1) & 3)) << 3;
      gload16(Abase + (size_t)row * K + k0 + kc, &As[(it * 256 + w * 64) * 8]);
      gload16(Bbase + (size_t)row * K + k0 + kc, &Bs[(it * 256 + w * 64) * 8]);
    }
    __syncthreads();
    bf16x8 af[4], bfr[4];
#pragma unroll
    for (int m = 0; m < 4; ++m) {
      int row = wy * 64 + m * 16 + lr;
      af[m] = *(const bf16x8*)(&As[row * 32 + ((g ^ ((row >> 1) & 3)) << 3)]);
    }
#pragma unroll
    for (int n = 0; n < 4; ++n) {
      int row = wx * 64 + n * 16 + lr;
      bfr[n] = *(const bf16x8*)(&Bs[row * 32 + ((g ^ ((row >> 1) & 3)) << 3)]);
    }
#pragma unroll
    for (int m = 0; m < 4; ++m)
#pragma unroll
      for (int n = 0; n < 4; ++n)
        acc[m][n] = __builtin_amdgcn_mfma_f32_16x16x32_bf16(af[m], bfr[n], acc[m][n], 0, 0, 0);
    __syncthreads();
  }

  // epilogue: C row = (lane>>4)*4 + j, col = lane&15 within each 16x16 frag
  const int colb = bn0 + wx * 64 + lr;
  const int rowb = bm0 + wy * 64 + (g << 2);
#pragma unroll
  for (int m = 0; m < 4; ++m) {
#pragma unroll
    for (int n = 0; n < 4; ++n) {
      int c = colb + n * 16;
      int r0 = rowb + m * 16;
      float bsv = (EPI == 2 || EPI == 3) ? bias[c] : 0.f;
#pragma unroll
      for (int j = 0; j < 4; ++j) {
        float vlu = acc[m][n][j] + bsv;
        size_t idx = (size_t)(r0 + j) * N + c;
        if (EPI == 0) ((float*)Cv)[idx] = vlu;
        else if (EPI == 1) ((float*)Cv)[idx] += vlu;
        else if (EPI == 2) ((__hip_bfloat16*)Cv)[idx] = __float2bfloat16(gelu_f(vlu));
        else ((float*)Cv)[idx] += vlu;
      }
    }
  }
}

// ---------------------------------------------------------------- LSH bucket ids
__global__ __launch_bounds__(128) void k_bucket(const float* __restrict__ qk,
                                                const float* __restrict__ rotL,
                                                unsigned char* __restrict__ bkt) {
  int blk = blockIdx.x;
  int tc = blk & 7, h = (blk >> 3) & 7, b = blk >> 6;
  int t0 = tc << 7;
  __shared__ float qs[128][65];
  __shared__ float rs[4096];
  int tid = threadIdx.x;
  for (int f = tid; f < 4096; f += 128) rs[f] = rotL[f];
  const float* base = qk + ((size_t)(b * T_ + t0)) * D_ + h * DH_;
  for (int f = tid; f < 2048; f += 128) {
    int rw = f >> 4, c4 = (f & 15) << 2;
    float4 v = *(const float4*)(base + (size_t)rw * D_ + c4);
    qs[rw][c4] = v.x; qs[rw][c4 + 1] = v.y; qs[rw][c4 + 2] = v.z; qs[rw][c4 + 3] = v.w;
  }
  __syncthreads();
  float s[64];
#pragma unroll
  for (int jr = 0; jr < 64; ++jr) s[jr] = 0.f;
  for (int d = 0; d < 64; ++d) {
    float q = qs[tid][d];
    const float* rp = rs + d * 64;
#pragma unroll
    for (int j4 = 0; j4 < 16; ++j4) {
      float4 rv = *(const float4*)(rp + j4 * 4);
      s[j4 * 4 + 0] += q * rv.x; s[j4 * 4 + 1] += q * rv.y;
      s[j4 * 4 + 2] += q * rv.z; s[j4 * 4 + 3] += q * rv.w;
    }
  }
  int bh = b * H_ + h;
#pragma unroll
  for (int r = 0; r < 8; ++r) {
    float best = s[r * 8];
    int bi = 0;
#pragma unroll
    for (int idx = 1; idx < 16; ++idx) {
      float v = (idx < 8) ? s[r * 8 + idx] : -s[r * 8 + idx - 8];
      if (v > best) { best = v; bi = idx; }
    }
    bkt[((size_t)(bh * NH_ + r)) * T_ + t0 + tid] = (unsigned char)bi;
  }
}

// ---------------------------------------------------------------- stable counting sort + undo
__global__ __launch_bounds__(1024) void k_sort(const unsigned char* __restrict__ bkt,
                                               int* __restrict__ st,
                                               int* __restrict__ undo) {
  int r = blockIdx.x & 7, bh = blockIdx.x >> 3;
  int t = threadIdx.x;
  int bk = bkt[((size_t)(bh * NH_ + r)) * T_ + t];
  int w = t >> 6, lane = t & 63;
  __shared__ int cnt[16][16];
  __shared__ int off[16][16];
  __shared__ int tot[16];
  __shared__ int stt[16];
  unsigned long long below = (1ULL << lane) - 1ULL;
  int myrank = 0;
#pragma unroll
  for (int bb = 0; bb < 16; ++bb) {
    unsigned long long m = __ballot(bk == bb);
    if (bk == bb) myrank = __popcll(m & below);
    if (lane == 0) cnt[w][bb] = __popcll(m);
  }
  __syncthreads();
  if (t < 16) {
    int run = 0;
    for (int ww = 0; ww < 16; ++ww) { off[ww][t] = run; run += cnt[ww][t]; }
    tot[t] = run;
  }
  __syncthreads();
  if (t == 0) {
    int run = 0;
    for (int bb = 0; bb < 16; ++bb) { stt[bb] = run; run += tot[bb]; }
  }
  __syncthreads();
  int pos = stt[bk] + off[w][bk] + myrank;
  st[((size_t)(bh * NH_ + r)) * T_ + pos] = t;
  undo[((size_t)(bh * NH_ + r)) * T_ + t] = pos;
}

// ---------------------------------------------------------------- chunked attention
// grid (c=128, bh=64); block 256; outputs written in SORTED order (coalesced, bf16)
__global__ __launch_bounds__(256) void k_attn(const float* __restrict__ qk,
                                              const float* __restrict__ vv,
                                              const int* __restrict__ st,
                                              __hip_bfloat16* __restrict__ ob,
                                              float* __restrict__ lgb) {
  int c = blockIdx.x, bh = blockIdx.y;
  int b = bh >> 3, h = bh & 7;
  int r = c >> 4;
  int pc = (c + NC_ - 1) & (NC_ - 1);
  __shared__ float KQ[128][68];
  __shared__ float Vs[128][68];
  __shared__ float inv[128];
  __shared__ int pos[128];
  int tid = threadIdx.x;
  if (tid < 128) {
    int j = tid;
    int sc = (j < 64) ? c : pc;
    int slot = ((sc & 15) << 6) + (j & 63);
    pos[j] = st[((size_t)(bh * NH_ + (sc >> 4))) * T_ + slot];
  }
  __syncthreads();
  const float* qkbase = qk + ((size_t)b * T_) * D_ + h * DH_;
  const float* vbase  = vv + ((size_t)b * T_) * D_ + h * DH_;
#pragma unroll
  for (int ld = 0; ld < 8; ++ld) {
    int f = ld * 256 + tid;
    int rw = f >> 4, c4 = (f & 15) << 2;
    int p0 = pos[rw];
    *(float4*)(&KQ[rw][c4]) = *(const float4*)(qkbase + (size_t)p0 * D_ + c4);
    *(float4*)(&Vs[rw][c4]) = *(const float4*)(vbase + (size_t)p0 * D_ + c4);
  }
  __syncthreads();
  if (tid < 128) {
    float ss = 0.f;
#pragma unroll
    for (int d4 = 0; d4 < 64; d4 += 4) {
      float4 v = *(const float4*)(&KQ[tid][d4]);
      ss += v.x * v.x + v.y * v.y + v.z * v.z + v.w * v.w;
    }
    inv[tid] = 1.0f / (sqrtf(ss) + 1e-8f);
  }
  __syncthreads();

  int i = tid >> 2, p = tid & 3;
  int mypos = pos[i];
  float dj[32];
#pragma unroll
  for (int jj = 0; jj < 32; ++jj) dj[jj] = 0.f;
#pragma unroll
  for (int d0 = 0; d0 < 64; d0 += 16) {
    float qreg[16];
    *(float4*)(qreg)      = *(const float4*)(&KQ[i][d0]);
    *(float4*)(qreg + 4)  = *(const float4*)(&KQ[i][d0 + 4]);
    *(float4*)(qreg + 8)  = *(const float4*)(&KQ[i][d0 + 8]);
    *(float4*)(qreg + 12) = *(const float4*)(&KQ[i][d0 + 12]);
#pragma unroll
    for (int jj = 0; jj < 32; ++jj) {
      int j = (jj << 2) + p;
      float kreg[16];
      *(float4*)(kreg)      = *(const float4*)(&KQ[j][d0]);
      *(float4*)(kreg + 4)  = *(const float4*)(&KQ[j][d0 + 4]);
      *(float4*)(kreg + 8)  = *(const float4*)(&KQ[j][d0 + 8]);
      *(float4*)(kreg + 12) = *(const float4*)(&KQ[j][d0 + 12]);
      float t0 = 0.f;
#pragma unroll
      for (int dd = 0; dd < 16; ++dd) t0 += qreg[dd] * kreg[dd];
      dj[jj] += t0;
    }
  }
  const float scale = 0.125f;
  float mloc = -3.0e38f;
#pragma unroll
  for (int jj = 0; jj < 32; ++jj) {
    int j = (jj << 2) + p;
    float dv = dj[jj] * inv[j] * scale;
    dv = (pos[j] == mypos) ? -5.0e4f : dv;
    dj[jj] = dv;
    mloc = fmaxf(mloc, dv);
  }
  mloc = fmaxf(mloc, __shfl_xor(mloc, 1));
  mloc = fmaxf(mloc, __shfl_xor(mloc, 2));
  float ls = 0.f;
#pragma unroll
  for (int jj = 0; jj < 32; ++jj) {
    float e = expf(dj[jj] - mloc);
    dj[jj] = e;
    ls += e;
  }
  ls += __shfl_xor(ls, 1);
  ls += __shfl_xor(ls, 2);
  float logit = mloc + logf(ls);
  float invl = 1.0f / ls;
  float acc[64];
#pragma unroll
  for (int d = 0; d < 64; ++d) acc[d] = 0.f;
#pragma unroll
  for (int jj = 0; jj < 32; ++jj) {
    int j = (jj << 2) + p;
    float wgt = dj[jj] * invl;
#pragma unroll
    for (int d4 = 0; d4 < 64; d4 += 4) {
      float4 v = *(const float4*)(&Vs[j][d4]);
      acc[d4 + 0] += wgt * v.x; acc[d4 + 1] += wgt * v.y;
      acc[d4 + 2] += wgt * v.z; acc[d4 + 3] += wgt * v.w;
    }
  }
#pragma unroll
  for (int d = 0; d < 64; ++d) {
    acc[d] += __shfl_xor(acc[d], 1);
    acc[d] += __shfl_xor(acc[d], 2);
  }
  int slot = ((c & 15) << 6) + i;
  __hip_bfloat16* orow = ob + (((size_t)(bh * NH_ + r)) * T_ + slot) * DH_;
  __hip_bfloat16 tmp[16];
#pragma unroll
  for (int dd = 0; dd < 16; ++dd) tmp[dd] = __float2bfloat16(acc[(p << 4) + dd]);
  *(uint4*)(orow + (p << 4))     = *(uint4*)(tmp);
  *(uint4*)(orow + (p << 4) + 8) = *(uint4*)(tmp + 8);
  if (p == 0) lgb[((size_t)(bh * NH_ + r)) * T_ + slot] = logit;
}

// ---------------------------------------------------------------- round combine (gather via undo)
__global__ __launch_bounds__(256) void k_combine(const __hip_bfloat16* __restrict__ ob,
                                                 const float* __restrict__ lgb,
                                                 const int* __restrict__ undo,
                                                 __hip_bfloat16* __restrict__ attnb) {
  int g = threadIdx.x >> 6, lane = threadIdx.x & 63;
  int idx = blockIdx.x * 4 + g;
  int bh = idx >> 10, t = idx & (T_ - 1);
  int b = bh >> 3, h = bh & 7;
  int su[8];
  float lg[8];
  float m = -3.0e38f;
#pragma unroll
  for (int r = 0; r < 8; ++r) {
    su[r] = undo[((size_t)(bh * NH_ + r)) * T_ + t];
    lg[r] = lgb[((size_t)(bh * NH_ + r)) * T_ + su[r]];
    m = fmaxf(m, lg[r]);
  }
  float s = 0.f;
#pragma unroll
  for (int r = 0; r < 8; ++r) { lg[r] = expf(lg[r] - m); s += lg[r]; }
  float invs = 1.0f / s;
  float o = 0.f;
#pragma unroll
  for (int r = 0; r < 8; ++r)
    o += lg[r] * invs * __bfloat162float(ob[(((size_t)(bh * NH_ + r)) * T_ + su[r]) * DH_ + lane]);
  attnb[((size_t)(b * T_ + t)) * D_ + h * DH_ + lane] = __float2bfloat16(o);
}

// ---------------------------------------------------------------- final reduction
__global__ void k_zero(float* __restrict__ p, int n) {
  int i = blockIdx.x * blockDim.x + threadIdx.x;
  if (i < n) p[i] = 0.f;
}

__global__ __launch_bounds__(256) void k_colsum(const float* __restrict__ xn,
                                                float* __restrict__ mean) {
  int b = blockIdx.x, dc = blockIdx.y, tc = blockIdx.z;
  int d = dc * 256 + threadIdx.x;
  float s = 0.f;
  for (int tt = 0; tt < 64; ++tt) {
    int t = tc * 64 + tt;
    s += xn[((size_t)(b * T_ + t)) * D_ + d];
  }
  atomicAdd(&mean[b * D_ + d], s);
}

__global__ __launch_bounds__(512) void k_fc(const float* __restrict__ mean,
                                            const float* __restrict__ Wfc,
                                            float* __restrict__ out) {
  int b = blockIdx.x, n = threadIdx.x;
  __shared__ float ms[512];
  ms[n] = mean[b * D_ + n] * (1.0f / 1024.0f);
  __syncthreads();
  float acc = 0.f;
  for (int d = 0; d < 512; ++d) acc += ms[d] * Wfc[(size_t)d * D_ + n];
  out[b * D_ + n] = acc;
}

// ---------------------------------------------------------------- launcher
extern "C" void kernel_launch(void* const* d_in, const int* in_sizes, int n_in,
                              void* d_out, int out_size, void* d_ws, size_t ws_size,
                              hipStream_t stream) {
  (void)in_sizes; (void)n_in; (void)out_size; (void)ws_size;
  const int*   ids  = (const int*)d_in[0];
  const float* te   = (const float*)d_in[1];
  const float* pe   = (const float*)d_in[2];
  const float* lag  = (const float*)d_in[3];
  const float* lab  = (const float*)d_in[4];
  const float* Wqk  = (const float*)d_in[5];
  const float* Wv   = (const float*)d_in[6];
  const float* Wo   = (const float*)d_in[7];
  const float* lfg  = (const float*)d_in[8];
  const float* lfb  = (const float*)d_in[9];
  const float* W1   = (const float*)d_in[10];
  const float* b1   = (const float*)d_in[11];
  const float* W2   = (const float*)d_in[12];
  const float* b2   = (const float*)d_in[13];
  const float* lnfg = (const float*)d_in[14];
  const float* lnfb = (const float*)d_in[15];
  const float* Wfc  = (const float*)d_in[16];
  const float* rot  = (const float*)d_in[17];

  char* ws = (char*)d_ws;
  size_t off = 0;
  auto carve = [&](size_t bytes) -> void* {
    void* p = ws + off;
    off += (bytes + 255) & ~(size_t)255;
    return p;
  };
  float* x1    = (float*)carve((size_t)ROWS_ * D_ * 4);
  float* x2    = (float*)carve((size_t)ROWS_ * D_ * 4);
  float* xn    = (float*)carve((size_t)ROWS_ * D_ * 4);
  float* qkb   = (float*)carve((size_t)ROWS_ * D_ * 4);
  float* vvb   = (float*)carve((size_t)ROWS_ * D_ * 4);
  __hip_bfloat16* xnb   = (__hip_bfloat16*)carve((size_t)ROWS_ * D_ * 2);
  __hip_bfloat16* attnb = (__hip_bfloat16*)carve((size_t)ROWS_ * D_ * 2);
  __hip_bfloat16* ob    = (__hip_bfloat16*)carve((size_t)BH_ * NH_ * T_ * DH_ * 2);  // 67 MB
  __hip_bfloat16* hid   = ob;  // alias: ob dead after combine; hid needs 32 MB
  unsigned char* bkt = (unsigned char*)carve((size_t)BH_ * NH_ * T_);
  int*   stb   = (int*)carve((size_t)BH_ * NH_ * T_ * 4);
  int*   undo  = (int*)carve((size_t)BH_ * NH_ * T_ * 4);
  float* lgb   = (float*)carve((size_t)BH_ * NH_ * T_ * 4);
  float* meanb = (float*)carve((size_t)B_ * D_ * 4);
  __hip_bfloat16* WvT = (__hip_bfloat16*)carve((size_t)DEPTH_ * D_ * D_ * 2);
  __hip_bfloat16* WoT = (__hip_bfloat16*)carve((size_t)DEPTH_ * D_ * D_ * 2);
  __hip_bfloat16* W1T = (__hip_bfloat16*)carve((size_t)DEPTH_ * D_ * FF_ * 2);
  __hip_bfloat16* W2T = (__hip_bfloat16*)carve((size_t)DEPTH_ * FF_ * D_ * 2);

  // weight convert+transpose (once per call)
  k_wt<<<dim3(D_ / 32, D_ / 32, DEPTH_), 256, 0, stream>>>(Wv, WvT, D_, D_);
  k_wt<<<dim3(D_ / 32, D_ / 32, DEPTH_), 256, 0, stream>>>(Wo, WoT, D_, D_);
  k_wt<<<dim3(FF_ / 32, D_ / 32, DEPTH_), 256, 0, stream>>>(W1, W1T, D_, FF_);
  k_wt<<<dim3(D_ / 32, FF_ / 32, DEPTH_), 256, 0, stream>>>(W2, W2T, FF_, D_);

  k_embed<<<ROWS_, 128, 0, stream>>>(ids, te, pe, x1, x2);

  for (int l = 0; l < DEPTH_; ++l) {
    const float* wqk = Wqk + (size_t)l * D_ * D_;
    const __hip_bfloat16* wvt = WvT + (size_t)l * D_ * D_;
    const __hip_bfloat16* wot = WoT + (size_t)l * D_ * D_;
    const __hip_bfloat16* w1t = W1T + (size_t)l * D_ * FF_;
    const __hip_bfloat16* w2t = W2T + (size_t)l * FF_ * D_;

    k_ln<<<ROWS_ / 4, 256, 0, stream>>>(x2, nullptr, lag + l * D_, lab + l * D_, xn, xnb);
    k_sgemm<<<dim3(D_ / 128, ROWS_ / 128), 256, 0, stream>>>(xn, wqk, qkb, D_, D_);
    k_bgemm<0><<<dim3(D_ / 128, ROWS_ / 128), 256, 0, stream>>>(xnb, wvt, nullptr, vvb, D_, D_);
    k_bucket<<<512, 128, 0, stream>>>(qkb, rot + (size_t)l * 4096, bkt);
    k_sort<<<512, 1024, 0, stream>>>(bkt, stb, undo);
    k_attn<<<dim3(NC_, BH_), 256, 0, stream>>>(qkb, vvb, stb, ob, lgb);
    k_combine<<<BH_ * T_ / 4, 256, 0, stream>>>(ob, lgb, undo, attnb);
    k_bgemm<1><<<dim3(D_ / 128, ROWS_ / 128), 256, 0, stream>>>(attnb, wot, nullptr, x1, D_, D_);

    k_ln<<<ROWS_ / 4, 256, 0, stream>>>(x1, nullptr, lfg + l * D_, lfb + l * D_, nullptr, xnb);
    k_bgemm<2><<<dim3(FF_ / 128, ROWS_ / 128), 256, 0, stream>>>(xnb, w1t, b1 + l * FF_, hid, FF_, D_);
    k_bgemm<3><<<dim3(D_ / 128, ROWS_ / 128), 256, 0, stream>>>(hid, w2t, b2 + l * D_, x2, D_, FF_);
  }

  k_ln<<<ROWS_ / 4, 256, 0, stream>>>(x1, x2, lnfg, lnfb, xn, nullptr);
  k_zero<<<16, 256, 0, stream>>>(meanb, B_ * D_);
  k_colsum<<<dim3(B_, 2, 16), 256, 0, stream>>>(xn, meanb);
  k_fc<<<B_, 512, 0, stream>>>(meanb, Wfc, (float*)d_out);
}

// Round 5
// 3312.351 us; speedup vs baseline: 2.9185x; 1.8177x over previous
//
#include <hip/hip_runtime.h>
#include <hip/hip_bf16.h>
#include <cstdint>
#include <cstddef>

#define B_ 8
#define T_ 1024
#define D_ 512
#define H_ 8
#define DH_ 64
#define DEPTH_ 8
#define FF_ 2048
#define NH_ 8
#define BS_ 64
#define NB_ 16
#define NC_ 128
#define BH_ 64
#define ROWS_ 8192   // B*T

typedef __attribute__((ext_vector_type(8))) short bf16x8;
typedef __attribute__((ext_vector_type(4))) float f32x4;

typedef __attribute__((address_space(1))) const unsigned int g_u32;
typedef __attribute__((address_space(3))) unsigned int l_u32;
__device__ __forceinline__ void gload16(const void* g, void* l) {
  __builtin_amdgcn_global_load_lds((g_u32*)g, (l_u32*)l, 16, 0, 0);
}

// ---------------------------------------------------------------- utilities
__device__ __forceinline__ float wave_sum(float v) {
#pragma unroll
  for (int o = 1; o < 64; o <<= 1) v += __shfl_xor(v, o);
  return v;
}

__device__ __forceinline__ float gelu_f(float u) {
  float c = u + 0.044715f * u * u * u;
  float t = tanhf(0.7978845608028654f * c);
  return 0.5f * u * (1.0f + t);
}

// ---------------------------------------------------------------- embedding
__global__ __launch_bounds__(128) void k_embed(const int* __restrict__ ids,
                                               const float* __restrict__ te,
                                               const float* __restrict__ pe,
                                               float* __restrict__ x1,
                                               float* __restrict__ x2) {
  int bt = blockIdx.x;
  int t = bt & (T_ - 1);
  int d = threadIdx.x * 4;
  int id = ids[bt];
  float4 v = *(const float4*)(te + (size_t)id * D_ + d);
  float4 p = *(const float4*)(pe + (size_t)t * D_ + d);
  v.x += p.x; v.y += p.y; v.z += p.z; v.w += p.w;
  *(float4*)(x1 + (size_t)bt * D_ + d) = v;
  *(float4*)(x2 + (size_t)bt * D_ + d) = v;
}

// ---------------------------------------------------------------- weight transpose + bf16
// in: W [K][N] fp32 ; out: WT [N][K] bf16 ; blockIdx.z = layer
__global__ __launch_bounds__(256) void k_wt(const float* __restrict__ W,
                                            __hip_bfloat16* __restrict__ WT,
                                            int K, int N) {
  const float* Wl = W + (size_t)blockIdx.z * K * N;
  __hip_bfloat16* WTl = WT + (size_t)blockIdx.z * K * N;
  __shared__ float tile[32][33];
  int n0 = blockIdx.x * 32, k0 = blockIdx.y * 32;
  int tx = threadIdx.x & 31, ty = threadIdx.x >> 5;  // 32 x 8
#pragma unroll
  for (int i = 0; i < 32; i += 8)
    tile[ty + i][tx] = Wl[(size_t)(k0 + ty + i) * N + n0 + tx];
  __syncthreads();
#pragma unroll
  for (int i = 0; i < 32; i += 8)
    WTl[(size_t)(n0 + ty + i) * K + k0 + tx] = __float2bfloat16(tile[tx][ty + i]);
}

// ---------------------------------------------------------------- layernorm
// one wave per row; if xb != null, input = 0.5*(x + xb); y (fp32) and yb (bf16) nullable
__global__ __launch_bounds__(256) void k_ln(const float* __restrict__ x,
                                            const float* __restrict__ xb,
                                            const float* __restrict__ g,
                                            const float* __restrict__ bb,
                                            float* __restrict__ y,
                                            __hip_bfloat16* __restrict__ yb) {
  int w = threadIdx.x >> 6, lane = threadIdx.x & 63;
  size_t row = (size_t)blockIdx.x * 4 + w;
  const float* xr = x + row * D_ + lane * 8;
  float v[8];
  *(float4*)(v)     = *(const float4*)(xr);
  *(float4*)(v + 4) = *(const float4*)(xr + 4);
  if (xb) {
    const float* x2r = xb + row * D_ + lane * 8;
    float u[8];
    *(float4*)(u)     = *(const float4*)(x2r);
    *(float4*)(u + 4) = *(const float4*)(x2r + 4);
#pragma unroll
    for (int i = 0; i < 8; ++i) v[i] = 0.5f * (v[i] + u[i]);
  }
  float s = 0.f;
#pragma unroll
  for (int i = 0; i < 8; ++i) s += v[i];
  s = wave_sum(s);
  float m = s * (1.0f / D_);
  float q = 0.f;
#pragma unroll
  for (int i = 0; i < 8; ++i) { float d = v[i] - m; q += d * d; }
  q = wave_sum(q);
  float inv = 1.0f / sqrtf(q * (1.0f / D_) + 1e-5f);
  float gg[8], bv[8];
  *(float4*)(gg)     = *(const float4*)(g + lane * 8);
  *(float4*)(gg + 4) = *(const float4*)(g + lane * 8 + 4);
  *(float4*)(bv)     = *(const float4*)(bb + lane * 8);
  *(float4*)(bv + 4) = *(const float4*)(bb + lane * 8 + 4);
  float o[8];
#pragma unroll
  for (int i = 0; i < 8; ++i) o[i] = (v[i] - m) * inv * gg[i] + bv[i];
  if (y) {
    float* yr = y + row * D_ + lane * 8;
    *(float4*)(yr)     = *(float4*)(o);
    *(float4*)(yr + 4) = *(float4*)(o + 4);
  }
  if (yb) {
    __hip_bfloat16 o16[8];
#pragma unroll
    for (int i = 0; i < 8; ++i) o16[i] = __float2bfloat16(o[i]);
    *(uint4*)(yb + row * D_ + lane * 8) = *(uint4*)o16;
  }
}

// ---------------------------------------------------------------- fp32 SGEMM (qk projection only)
__global__ __launch_bounds__(256) void k_sgemm(const float* __restrict__ A,
                                               const float* __restrict__ Bm,
                                               float* __restrict__ C,
                                               int N, int K) {
  __shared__ float As[32][128];
  __shared__ float Bs[32][128];
  const int bn0 = blockIdx.x * 128;
  const int bm0 = blockIdx.y * 128;
  const int tid = threadIdx.x;
  const int w = tid >> 6, lane = tid & 63;
  const int wy = w >> 1, wx = w & 1;
  const int ly = lane >> 3, lx = lane & 7;
  const int rm = wy * 64 + ly * 8;
  const int cn = wx * 64 + lx * 8;
  float acc[8][8] = {};

  for (int k0 = 0; k0 < K; k0 += 32) {
#pragma unroll
    for (int ld = 0; ld < 4; ++ld) {
      int f = tid + ld * 256;
      int ar = f >> 3;
      int ac = (f & 7) << 2;
      float4 av = *(const float4*)(A + (size_t)(bm0 + ar) * K + k0 + ac);
      As[ac + 0][ar] = av.x; As[ac + 1][ar] = av.y;
      As[ac + 2][ar] = av.z; As[ac + 3][ar] = av.w;
      int br = f >> 5;
      int bc = (f & 31) << 2;
      *(float4*)(&Bs[br][bc]) = *(const float4*)(Bm + (size_t)(k0 + br) * N + bn0 + bc);
    }
    __syncthreads();
#pragma unroll
    for (int kk = 0; kk < 32; ++kk) {
      float a[8], b[8];
      *(float4*)(a)     = *(const float4*)(&As[kk][rm]);
      *(float4*)(a + 4) = *(const float4*)(&As[kk][rm + 4]);
      *(float4*)(b)     = *(const float4*)(&Bs[kk][cn]);
      *(float4*)(b + 4) = *(const float4*)(&Bs[kk][cn + 4]);
#pragma unroll
      for (int i = 0; i < 8; ++i)
#pragma unroll
        for (int j = 0; j < 8; ++j) acc[i][j] += a[i] * b[j];
    }
    __syncthreads();
  }
#pragma unroll
  for (int i = 0; i < 8; ++i) {
    float* crow = C + (size_t)(bm0 + rm + i) * N + bn0 + cn;
#pragma unroll
    for (int j0 = 0; j0 < 8; j0 += 4)
      *(float4*)(crow + j0) = make_float4(acc[i][j0], acc[i][j0 + 1], acc[i][j0 + 2], acc[i][j0 + 3]);
  }
}

// ---------------------------------------------------------------- bf16 MFMA GEMM
// C[M,N] = A[M,K](bf16) x BT[N,K](bf16); BM=BN=128, BK=32, 256 thr (2x2 waves, 64x64/wave)
// EPI: 0 C(f32)=AB ; 1 C(f32)+=AB ; 2 C(bf16)=gelu(AB+bias) ; 3 C(f32)+=AB+bias
template <int EPI>
__global__ __launch_bounds__(256) void k_bgemm(const __hip_bfloat16* __restrict__ A,
                                               const __hip_bfloat16* __restrict__ BT,
                                               const float* __restrict__ bias,
                                               void* __restrict__ Cv,
                                               int N, int K) {
  __shared__ __align__(16) __hip_bfloat16 As[128 * 32];
  __shared__ __align__(16) __hip_bfloat16 Bs[128 * 32];
  const int bn0 = blockIdx.x * 128;
  const int bm0 = blockIdx.y * 128;
  const int tid = threadIdx.x;
  const int w = tid >> 6, lane = tid & 63;
  const int wy = w >> 1, wx = w & 1;
  const int g = lane >> 4, lr = lane & 15;
  f32x4 acc[4][4] = {};

  const __hip_bfloat16* Abase = A + (size_t)bm0 * K;
  const __hip_bfloat16* Bbase = BT + (size_t)bn0 * K;

  for (int k0 = 0; k0 < K; k0 += 32) {
#pragma unroll
    for (int it = 0; it < 2; ++it) {
      int f = it * 256 + w * 64 + lane;
      int row = f >> 2;
      int kc = ((f & 3) ^ ((row >> 1) & 3)) << 3;
      gload16(Abase + (size_t)row * K + k0 + kc, &As[(it * 256 + w * 64) * 8]);
      gload16(Bbase + (size_t)row * K + k0 + kc, &Bs[(it * 256 + w * 64) * 8]);
    }
    __syncthreads();
    bf16x8 af[4], bfr[4];
#pragma unroll
    for (int m = 0; m < 4; ++m) {
      int row = wy * 64 + m * 16 + lr;
      af[m] = *(const bf16x8*)(&As[row * 32 + ((g ^ ((row >> 1) & 3)) << 3)]);
    }
#pragma unroll
    for (int n = 0; n < 4; ++n) {
      int row = wx * 64 + n * 16 + lr;
      bfr[n] = *(const bf16x8*)(&Bs[row * 32 + ((g ^ ((row >> 1) & 3)) << 3)]);
    }
#pragma unroll
    for (int m = 0; m < 4; ++m)
#pragma unroll
      for (int n = 0; n < 4; ++n)
        acc[m][n] = __builtin_amdgcn_mfma_f32_16x16x32_bf16(af[m], bfr[n], acc[m][n], 0, 0, 0);
    __syncthreads();
  }

  const int colb = bn0 + wx * 64 + lr;
  const int rowb = bm0 + wy * 64 + (g << 2);
#pragma unroll
  for (int m = 0; m < 4; ++m) {
#pragma unroll
    for (int n = 0; n < 4; ++n) {
      int c = colb + n * 16;
      int r0 = rowb + m * 16;
      float bsv = (EPI == 2 || EPI == 3) ? bias[c] : 0.f;
#pragma unroll
      for (int j = 0; j < 4; ++j) {
        float vlu = acc[m][n][j] + bsv;
        size_t idx = (size_t)(r0 + j) * N + c;
        if (EPI == 0) ((float*)Cv)[idx] = vlu;
        else if (EPI == 1) ((float*)Cv)[idx] += vlu;
        else if (EPI == 2) ((__hip_bfloat16*)Cv)[idx] = __float2bfloat16(gelu_f(vlu));
        else ((float*)Cv)[idx] += vlu;
      }
    }
  }
}

// ---------------------------------------------------------------- LSH bucket ids
__global__ __launch_bounds__(128) void k_bucket(const float* __restrict__ qk,
                                                const float* __restrict__ rotL,
                                                unsigned char* __restrict__ bkt) {
  int blk = blockIdx.x;
  int tc = blk & 7, h = (blk >> 3) & 7, b = blk >> 6;
  int t0 = tc << 7;
  __shared__ float qs[128][65];
  __shared__ float rs[4096];
  int tid = threadIdx.x;
  for (int f = tid; f < 4096; f += 128) rs[f] = rotL[f];
  const float* base = qk + ((size_t)(b * T_ + t0)) * D_ + h * DH_;
  for (int f = tid; f < 2048; f += 128) {
    int rw = f >> 4, c4 = (f & 15) << 2;
    float4 v = *(const float4*)(base + (size_t)rw * D_ + c4);
    qs[rw][c4] = v.x; qs[rw][c4 + 1] = v.y; qs[rw][c4 + 2] = v.z; qs[rw][c4 + 3] = v.w;
  }
  __syncthreads();
  float s[64];
#pragma unroll
  for (int jr = 0; jr < 64; ++jr) s[jr] = 0.f;
  for (int d = 0; d < 64; ++d) {
    float q = qs[tid][d];
    const float* rp = rs + d * 64;
#pragma unroll
    for (int j4 = 0; j4 < 16; ++j4) {
      float4 rv = *(const float4*)(rp + j4 * 4);
      s[j4 * 4 + 0] += q * rv.x; s[j4 * 4 + 1] += q * rv.y;
      s[j4 * 4 + 2] += q * rv.z; s[j4 * 4 + 3] += q * rv.w;
    }
  }
  int bh = b * H_ + h;
#pragma unroll
  for (int r = 0; r < 8; ++r) {
    float best = s[r * 8];
    int bi = 0;
#pragma unroll
    for (int idx = 1; idx < 16; ++idx) {
      float v = (idx < 8) ? s[r * 8 + idx] : -s[r * 8 + idx - 8];
      if (v > best) { best = v; bi = idx; }
    }
    bkt[((size_t)(bh * NH_ + r)) * T_ + t0 + tid] = (unsigned char)bi;
  }
}

// ---------------------------------------------------------------- stable counting sort + undo
__global__ __launch_bounds__(1024) void k_sort(const unsigned char* __restrict__ bkt,
                                               int* __restrict__ st,
                                               int* __restrict__ undo) {
  int r = blockIdx.x & 7, bh = blockIdx.x >> 3;
  int t = threadIdx.x;
  int bk = bkt[((size_t)(bh * NH_ + r)) * T_ + t];
  int w = t >> 6, lane = t & 63;
  __shared__ int cnt[16][16];
  __shared__ int off[16][16];
  __shared__ int tot[16];
  __shared__ int stt[16];
  unsigned long long below = (1ULL << lane) - 1ULL;
  int myrank = 0;
#pragma unroll
  for (int bb = 0; bb < 16; ++bb) {
    unsigned long long m = __ballot(bk == bb);
    if (bk == bb) myrank = __popcll(m & below);
    if (lane == 0) cnt[w][bb] = __popcll(m);
  }
  __syncthreads();
  if (t < 16) {
    int run = 0;
    for (int ww = 0; ww < 16; ++ww) { off[ww][t] = run; run += cnt[ww][t]; }
    tot[t] = run;
  }
  __syncthreads();
  if (t == 0) {
    int run = 0;
    for (int bb = 0; bb < 16; ++bb) { stt[bb] = run; run += tot[bb]; }
  }
  __syncthreads();
  int pos = stt[bk] + off[w][bk] + myrank;
  st[((size_t)(bh * NH_ + r)) * T_ + pos] = t;
  undo[((size_t)(bh * NH_ + r)) * T_ + t] = pos;
}

// ---------------------------------------------------------------- chunked attention (MFMA)
// grid (c=128, bh=64); block 256 (4 waves). 64 q x 128 keys per chunk.
// K normalized+bf16 (norm in fp32 from regs), Q bf16 with 0.125 folded, V bf16 transposed.
// dots: D[q][k] = Q x Kb^T per validated k_bgemm fragment pattern.
// PV:   O^T[d][q] = V^T x P^T, both operands read row-major [outer][kdim].
// Softmax fp32 in regs; probs bf16 via LDS tile overlaid on dead Q.
__global__ __launch_bounds__(256) void k_attn(const float* __restrict__ qk,
                                              const float* __restrict__ vv,
                                              const int* __restrict__ st,
                                              __hip_bfloat16* __restrict__ ob,
                                              float* __restrict__ lgb) {
  // strides: Kb/Qb 72 elems (144 B), VbT/Pb 136 elems (272 B) -> <=2-way banks
  __shared__ __align__(16) __hip_bfloat16 Kb[128 * 72];     // 18432 B
  __shared__ __align__(16) __hip_bfloat16 VbT[64 * 136];    // 17408 B
  __shared__ __align__(16) __hip_bfloat16 PbQb[64 * 136];   // 17408 B (Qb stride 72 first, Pb stride 136 after)
  __shared__ int pos[128];

  const int c = blockIdx.x, bh = blockIdx.y;
  const int b = bh >> 3, h = bh & 7;
  const int r = c >> 4;
  const int pc = (c + NC_ - 1) & (NC_ - 1);
  const int tid = threadIdx.x;

  if (tid < 128) {
    int sc = (tid < 64) ? c : pc;
    int slot = ((sc & 15) << 6) + (tid & 63);
    pos[tid] = st[((size_t)(bh * NH_ + (sc >> 4))) * T_ + slot];
  }
  __syncthreads();

  const float* qkbase = qk + ((size_t)b * T_) * D_ + h * DH_;
  const float* vbase  = vv + ((size_t)b * T_) * D_ + h * DH_;

  // --- K: gather fp32, normalize (16-lane shuffle reduce), bf16 -> Kb[key][d]
#pragma unroll
  for (int ld = 0; ld < 8; ++ld) {
    int f = ld * 256 + tid;
    int rw = f >> 4, c4 = (f & 15) << 2;
    float4 v = *(const float4*)(qkbase + (size_t)pos[rw] * D_ + c4);
    float ss = v.x * v.x + v.y * v.y + v.z * v.z + v.w * v.w;
    ss += __shfl_xor(ss, 1); ss += __shfl_xor(ss, 2);
    ss += __shfl_xor(ss, 4); ss += __shfl_xor(ss, 8);
    float inv = 1.0f / (sqrtf(ss) + 1e-8f);
    __hip_bfloat16 kb4[4];
    kb4[0] = __float2bfloat16(v.x * inv); kb4[1] = __float2bfloat16(v.y * inv);
    kb4[2] = __float2bfloat16(v.z * inv); kb4[3] = __float2bfloat16(v.w * inv);
    *(uint2*)(&Kb[rw * 72 + c4]) = *(uint2*)kb4;
  }
  // --- Q: rows pos[0..63], x0.125, bf16 -> Qb (=PbQb, stride 72)
#pragma unroll
  for (int ld = 0; ld < 4; ++ld) {
    int f = ld * 256 + tid;
    int rw = f >> 4, c4 = (f & 15) << 2;
    float4 v = *(const float4*)(qkbase + (size_t)pos[rw] * D_ + c4);
    __hip_bfloat16 qb4[4];
    qb4[0] = __float2bfloat16(v.x * 0.125f); qb4[1] = __float2bfloat16(v.y * 0.125f);
    qb4[2] = __float2bfloat16(v.z * 0.125f); qb4[3] = __float2bfloat16(v.w * 0.125f);
    *(uint2*)(&PbQb[rw * 72 + c4]) = *(uint2*)qb4;
  }
  // --- V: gather fp32, bf16, TRANSPOSED -> VbT[d][key]
#pragma unroll
  for (int ld = 0; ld < 8; ++ld) {
    int f = ld * 256 + tid;
    int rw = f >> 4, c4 = (f & 15) << 2;
    float4 v = *(const float4*)(vbase + (size_t)pos[rw] * D_ + c4);
    VbT[(c4 + 0) * 136 + rw] = __float2bfloat16(v.x);
    VbT[(c4 + 1) * 136 + rw] = __float2bfloat16(v.y);
    VbT[(c4 + 2) * 136 + rw] = __float2bfloat16(v.z);
    VbT[(c4 + 3) * 136 + rw] = __float2bfloat16(v.w);
  }
  __syncthreads();

  const int w = tid >> 6, lane = tid & 63;
  const int g = lane >> 4, l15 = lane & 15;
  const int q0 = w * 16;

  // --- dots: wave w computes q rows q0..q0+15 x all 128 keys
  bf16x8 af0 = *(const bf16x8*)(&PbQb[(q0 + l15) * 72 + g * 8]);
  bf16x8 af1 = *(const bf16x8*)(&PbQb[(q0 + l15) * 72 + 32 + g * 8]);
  f32x4 dacc[8];
#pragma unroll
  for (int n = 0; n < 8; ++n) dacc[n] = (f32x4){0.f, 0.f, 0.f, 0.f};
#pragma unroll
  for (int n = 0; n < 8; ++n) {
    bf16x8 b0 = *(const bf16x8*)(&Kb[(n * 16 + l15) * 72 + g * 8]);
    bf16x8 b1 = *(const bf16x8*)(&Kb[(n * 16 + l15) * 72 + 32 + g * 8]);
    dacc[n] = __builtin_amdgcn_mfma_f32_16x16x32_bf16(af0, b0, dacc[n], 0, 0, 0);
    dacc[n] = __builtin_amdgcn_mfma_f32_16x16x32_bf16(af1, b1, dacc[n], 0, 0, 0);
  }
  __syncthreads();   // all Qb reads done before Pb overwrites the region

  // --- mask + softmax (fp32, in regs). lane holds rows q0+g*4+reg, keys 16n+l15
  int qpos[4], kpos[8];
#pragma unroll
  for (int reg = 0; reg < 4; ++reg) qpos[reg] = pos[q0 + g * 4 + reg];
#pragma unroll
  for (int n = 0; n < 8; ++n) kpos[n] = pos[n * 16 + l15];
  float pr[8][4];
  float lgt[4];
#pragma unroll
  for (int reg = 0; reg < 4; ++reg) {
    float mx = -3.0e38f;
#pragma unroll
    for (int n = 0; n < 8; ++n) {
      float dv = dacc[n][reg];
      dv = (kpos[n] == qpos[reg]) ? -5.0e4f : dv;
      pr[n][reg] = dv;
      mx = fmaxf(mx, dv);
    }
    mx = fmaxf(mx, __shfl_xor(mx, 1));
    mx = fmaxf(mx, __shfl_xor(mx, 2));
    mx = fmaxf(mx, __shfl_xor(mx, 4));
    mx = fmaxf(mx, __shfl_xor(mx, 8));
    float s = 0.f;
#pragma unroll
    for (int n = 0; n < 8; ++n) { float e = expf(pr[n][reg] - mx); pr[n][reg] = e; s += e; }
    s += __shfl_xor(s, 1); s += __shfl_xor(s, 2);
    s += __shfl_xor(s, 4); s += __shfl_xor(s, 8);
    lgt[reg] = mx + logf(s);
    float isc = 1.0f / s;
#pragma unroll
    for (int n = 0; n < 8; ++n) pr[n][reg] *= isc;
  }
  // probs -> Pb (bf16, stride 136)
#pragma unroll
  for (int n = 0; n < 8; ++n)
#pragma unroll
    for (int reg = 0; reg < 4; ++reg)
      PbQb[(q0 + g * 4 + reg) * 136 + n * 16 + l15] = __float2bfloat16(pr[n][reg]);
  const size_t slotbase = ((size_t)(bh * NH_ + r)) * T_ + ((c & 15) << 6);
  if (l15 == 0) {
#pragma unroll
    for (int reg = 0; reg < 4; ++reg)
      lgb[slotbase + q0 + g * 4 + reg] = lgt[reg];
  }
  __syncthreads();

  // --- PV: wave w computes O^T rows d=16w..16w+15 x all 64 q
  bf16x8 va[4];
#pragma unroll
  for (int s = 0; s < 4; ++s)
    va[s] = *(const bf16x8*)(&VbT[(w * 16 + l15) * 136 + s * 32 + g * 8]);
#pragma unroll
  for (int n = 0; n < 4; ++n) {
    f32x4 oa = (f32x4){0.f, 0.f, 0.f, 0.f};
#pragma unroll
    for (int s = 0; s < 4; ++s) {
      bf16x8 pb = *(const bf16x8*)(&PbQb[(n * 16 + l15) * 136 + s * 32 + g * 8]);
      oa = __builtin_amdgcn_mfma_f32_16x16x32_bf16(va[s], pb, oa, 0, 0, 0);
    }
    int q = n * 16 + l15;             // D col = l15
    int d = w * 16 + g * 4;           // D row = g*4 + reg
    __hip_bfloat16 o4[4];
#pragma unroll
    for (int reg = 0; reg < 4; ++reg) o4[reg] = __float2bfloat16(oa[reg]);
    *(uint2*)(&ob[(slotbase + q) * DH_ + d]) = *(uint2*)o4;
  }
}

// ---------------------------------------------------------------- round combine (gather via undo)
__global__ __launch_bounds__(256) void k_combine(const __hip_bfloat16* __restrict__ ob,
                                                 const float* __restrict__ lgb,
                                                 const int* __restrict__ undo,
                                                 __hip_bfloat16* __restrict__ attnb) {
  int g = threadIdx.x >> 6, lane = threadIdx.x & 63;
  int idx = blockIdx.x * 4 + g;
  int bh = idx >> 10, t = idx & (T_ - 1);
  int b = bh >> 3, h = bh & 7;
  int su[8];
  float lg[8];
  float m = -3.0e38f;
#pragma unroll
  for (int r = 0; r < 8; ++r) {
    su[r] = undo[((size_t)(bh * NH_ + r)) * T_ + t];
    lg[r] = lgb[((size_t)(bh * NH_ + r)) * T_ + su[r]];
    m = fmaxf(m, lg[r]);
  }
  float s = 0.f;
#pragma unroll
  for (int r = 0; r < 8; ++r) { lg[r] = expf(lg[r] - m); s += lg[r]; }
  float invs = 1.0f / s;
  float o = 0.f;
#pragma unroll
  for (int r = 0; r < 8; ++r)
    o += lg[r] * invs * __bfloat162float(ob[(((size_t)(bh * NH_ + r)) * T_ + su[r]) * DH_ + lane]);
  attnb[((size_t)(b * T_ + t)) * D_ + h * DH_ + lane] = __float2bfloat16(o);
}

// ---------------------------------------------------------------- final reduction
__global__ void k_zero(float* __restrict__ p, int n) {
  int i = blockIdx.x * blockDim.x + threadIdx.x;
  if (i < n) p[i] = 0.f;
}

__global__ __launch_bounds__(256) void k_colsum(const float* __restrict__ xn,
                                                float* __restrict__ mean) {
  int b = blockIdx.x, dc = blockIdx.y, tc = blockIdx.z;
  int d = dc * 256 + threadIdx.x;
  float s = 0.f;
  for (int tt = 0; tt < 64; ++tt) {
    int t = tc * 64 + tt;
    s += xn[((size_t)(b * T_ + t)) * D_ + d];
  }
  atomicAdd(&mean[b * D_ + d], s);
}

__global__ __launch_bounds__(512) void k_fc(const float* __restrict__ mean,
                                            const float* __restrict__ Wfc,
                                            float* __restrict__ out) {
  int b = blockIdx.x, n = threadIdx.x;
  __shared__ float ms[512];
  ms[n] = mean[b * D_ + n] * (1.0f / 1024.0f);
  __syncthreads();
  float acc = 0.f;
  for (int d = 0; d < 512; ++d) acc += ms[d] * Wfc[(size_t)d * D_ + n];
  out[b * D_ + n] = acc;
}

// ---------------------------------------------------------------- launcher
extern "C" void kernel_launch(void* const* d_in, const int* in_sizes, int n_in,
                              void* d_out, int out_size, void* d_ws, size_t ws_size,
                              hipStream_t stream) {
  (void)in_sizes; (void)n_in; (void)out_size; (void)ws_size;
  const int*   ids  = (const int*)d_in[0];
  const float* te   = (const float*)d_in[1];
  const float* pe   = (const float*)d_in[2];
  const float* lag  = (const float*)d_in[3];
  const float* lab  = (const float*)d_in[4];
  const float* Wqk  = (const float*)d_in[5];
  const float* Wv   = (const float*)d_in[6];
  const float* Wo   = (const float*)d_in[7];
  const float* lfg  = (const float*)d_in[8];
  const float* lfb  = (const float*)d_in[9];
  const float* W1   = (const float*)d_in[10];
  const float* b1   = (const float*)d_in[11];
  const float* W2   = (const float*)d_in[12];
  const float* b2   = (const float*)d_in[13];
  const float* lnfg = (const float*)d_in[14];
  const float* lnfb = (const float*)d_in[15];
  const float* Wfc  = (const float*)d_in[16];
  const float* rot  = (const float*)d_in[17];

  char* ws = (char*)d_ws;
  size_t off = 0;
  auto carve = [&](size_t bytes) -> void* {
    void* p = ws + off;
    off += (bytes + 255) & ~(size_t)255;
    return p;
  };
  float* x1    = (float*)carve((size_t)ROWS_ * D_ * 4);
  float* x2    = (float*)carve((size_t)ROWS_ * D_ * 4);
  float* xn    = (float*)carve((size_t)ROWS_ * D_ * 4);
  float* qkb   = (float*)carve((size_t)ROWS_ * D_ * 4);
  float* vvb   = (float*)carve((size_t)ROWS_ * D_ * 4);
  __hip_bfloat16* xnb   = (__hip_bfloat16*)carve((size_t)ROWS_ * D_ * 2);
  __hip_bfloat16* attnb = (__hip_bfloat16*)carve((size_t)ROWS_ * D_ * 2);
  __hip_bfloat16* ob    = (__hip_bfloat16*)carve((size_t)BH_ * NH_ * T_ * DH_ * 2);  // 67 MB
  __hip_bfloat16* hid   = ob;  // alias: ob dead after combine; hid needs 32 MB
  unsigned char* bkt = (unsigned char*)carve((size_t)BH_ * NH_ * T_);
  int*   stb   = (int*)carve((size_t)BH_ * NH_ * T_ * 4);
  int*   undo  = (int*)carve((size_t)BH_ * NH_ * T_ * 4);
  float* lgb   = (float*)carve((size_t)BH_ * NH_ * T_ * 4);
  float* meanb = (float*)carve((size_t)B_ * D_ * 4);
  __hip_bfloat16* WvT = (__hip_bfloat16*)carve((size_t)DEPTH_ * D_ * D_ * 2);
  __hip_bfloat16* WoT = (__hip_bfloat16*)carve((size_t)DEPTH_ * D_ * D_ * 2);
  __hip_bfloat16* W1T = (__hip_bfloat16*)carve((size_t)DEPTH_ * D_ * FF_ * 2);
  __hip_bfloat16* W2T = (__hip_bfloat16*)carve((size_t)DEPTH_ * FF_ * D_ * 2);

  k_wt<<<dim3(D_ / 32, D_ / 32, DEPTH_), 256, 0, stream>>>(Wv, WvT, D_, D_);
  k_wt<<<dim3(D_ / 32, D_ / 32, DEPTH_), 256, 0, stream>>>(Wo, WoT, D_, D_);
  k_wt<<<dim3(FF_ / 32, D_ / 32, DEPTH_), 256, 0, stream>>>(W1, W1T, D_, FF_);
  k_wt<<<dim3(D_ / 32, FF_ / 32, DEPTH_), 256, 0, stream>>>(W2, W2T, FF_, D_);

  k_embed<<<ROWS_, 128, 0, stream>>>(ids, te, pe, x1, x2);

  for (int l = 0; l < DEPTH_; ++l) {
    const float* wqk = Wqk + (size_t)l * D_ * D_;
    const __hip_bfloat16* wvt = WvT + (size_t)l * D_ * D_;
    const __hip_bfloat16* wot = WoT + (size_t)l * D_ * D_;
    const __hip_bfloat16* w1t = W1T + (size_t)l * D_ * FF_;
    const __hip_bfloat16* w2t = W2T + (size_t)l * FF_ * D_;

    k_ln<<<ROWS_ / 4, 256, 0, stream>>>(x2, nullptr, lag + l * D_, lab + l * D_, xn, xnb);
    k_sgemm<<<dim3(D_ / 128, ROWS_ / 128), 256, 0, stream>>>(xn, wqk, qkb, D_, D_);
    k_bgemm<0><<<dim3(D_ / 128, ROWS_ / 128), 256, 0, stream>>>(xnb, wvt, nullptr, vvb, D_, D_);
    k_bucket<<<512, 128, 0, stream>>>(qkb, rot + (size_t)l * 4096, bkt);
    k_sort<<<512, 1024, 0, stream>>>(bkt, stb, undo);
    k_attn<<<dim3(NC_, BH_), 256, 0, stream>>>(qkb, vvb, stb, ob, lgb);
    k_combine<<<BH_ * T_ / 4, 256, 0, stream>>>(ob, lgb, undo, attnb);
    k_bgemm<1><<<dim3(D_ / 128, ROWS_ / 128), 256, 0, stream>>>(attnb, wot, nullptr, x1, D_, D_);

    k_ln<<<ROWS_ / 4, 256, 0, stream>>>(x1, nullptr, lfg + l * D_, lfb + l * D_, nullptr, xnb);
    k_bgemm<2><<<dim3(FF_ / 128, ROWS_ / 128), 256, 0, stream>>>(xnb, w1t, b1 + l * FF_, hid, FF_, D_);
    k_bgemm<3><<<dim3(D_ / 128, ROWS_ / 128), 256, 0, stream>>>(hid, w2t, b2 + l * D_, x2, D_, FF_);
  }

  k_ln<<<ROWS_ / 4, 256, 0, stream>>>(x1, x2, lnfg, lnfb, xn, nullptr);
  k_zero<<<16, 256, 0, stream>>>(meanb, B_ * D_);
  k_colsum<<<dim3(B_, 2, 16), 256, 0, stream>>>(xn, meanb);
  k_fc<<<B_, 512, 0, stream>>>(meanb, Wfc, (float*)d_out);
}

// Round 6
// 3200.003 us; speedup vs baseline: 3.0209x; 1.0351x over previous
//
#include <hip/hip_runtime.h>
#include <hip/hip_bf16.h>
#include <cstdint>
#include <cstddef>

#define B_ 8
#define T_ 1024
#define D_ 512
#define H_ 8
#define DH_ 64
#define DEPTH_ 8
#define FF_ 2048
#define NH_ 8
#define BS_ 64
#define NB_ 16
#define NC_ 128
#define BH_ 64
#define ROWS_ 8192   // B*T

typedef __attribute__((ext_vector_type(8))) short bf16x8;
typedef __attribute__((ext_vector_type(4))) float f32x4;

typedef __attribute__((address_space(1))) const unsigned int g_u32;
typedef __attribute__((address_space(3))) unsigned int l_u32;
__device__ __forceinline__ void gload16(const void* g, void* l) {
  __builtin_amdgcn_global_load_lds((g_u32*)g, (l_u32*)l, 16, 0, 0);
}

// ---------------------------------------------------------------- utilities
__device__ __forceinline__ float wave_sum(float v) {
#pragma unroll
  for (int o = 1; o < 64; o <<= 1) v += __shfl_xor(v, o);
  return v;
}

__device__ __forceinline__ float gelu_f(float u) {
  float c = u + 0.044715f * u * u * u;
  float t = tanhf(0.7978845608028654f * c);
  return 0.5f * u * (1.0f + t);
}

// ---------------------------------------------------------------- embedding
__global__ __launch_bounds__(128) void k_embed(const int* __restrict__ ids,
                                               const float* __restrict__ te,
                                               const float* __restrict__ pe,
                                               float* __restrict__ x1,
                                               float* __restrict__ x2) {
  int bt = blockIdx.x;
  int t = bt & (T_ - 1);
  int d = threadIdx.x * 4;
  int id = ids[bt];
  float4 v = *(const float4*)(te + (size_t)id * D_ + d);
  float4 p = *(const float4*)(pe + (size_t)t * D_ + d);
  v.x += p.x; v.y += p.y; v.z += p.z; v.w += p.w;
  *(float4*)(x1 + (size_t)bt * D_ + d) = v;
  *(float4*)(x2 + (size_t)bt * D_ + d) = v;
}

// ---------------------------------------------------------------- weight transpose + bf16
__global__ __launch_bounds__(256) void k_wt(const float* __restrict__ W,
                                            __hip_bfloat16* __restrict__ WT,
                                            int K, int N) {
  const float* Wl = W + (size_t)blockIdx.z * K * N;
  __hip_bfloat16* WTl = WT + (size_t)blockIdx.z * K * N;
  __shared__ float tile[32][33];
  int n0 = blockIdx.x * 32, k0 = blockIdx.y * 32;
  int tx = threadIdx.x & 31, ty = threadIdx.x >> 5;  // 32 x 8
#pragma unroll
  for (int i = 0; i < 32; i += 8)
    tile[ty + i][tx] = Wl[(size_t)(k0 + ty + i) * N + n0 + tx];
  __syncthreads();
#pragma unroll
  for (int i = 0; i < 32; i += 8)
    WTl[(size_t)(n0 + ty + i) * K + k0 + tx] = __float2bfloat16(tile[tx][ty + i]);
}

// ---------------------------------------------------------------- layernorm
__global__ __launch_bounds__(256) void k_ln(const float* __restrict__ x,
                                            const float* __restrict__ xb,
                                            const float* __restrict__ g,
                                            const float* __restrict__ bb,
                                            float* __restrict__ y,
                                            __hip_bfloat16* __restrict__ yb) {
  int w = threadIdx.x >> 6, lane = threadIdx.x & 63;
  size_t row = (size_t)blockIdx.x * 4 + w;
  const float* xr = x + row * D_ + lane * 8;
  float v[8];
  *(float4*)(v)     = *(const float4*)(xr);
  *(float4*)(v + 4) = *(const float4*)(xr + 4);
  if (xb) {
    const float* x2r = xb + row * D_ + lane * 8;
    float u[8];
    *(float4*)(u)     = *(const float4*)(x2r);
    *(float4*)(u + 4) = *(const float4*)(x2r + 4);
#pragma unroll
    for (int i = 0; i < 8; ++i) v[i] = 0.5f * (v[i] + u[i]);
  }
  float s = 0.f;
#pragma unroll
  for (int i = 0; i < 8; ++i) s += v[i];
  s = wave_sum(s);
  float m = s * (1.0f / D_);
  float q = 0.f;
#pragma unroll
  for (int i = 0; i < 8; ++i) { float d = v[i] - m; q += d * d; }
  q = wave_sum(q);
  float inv = 1.0f / sqrtf(q * (1.0f / D_) + 1e-5f);
  float gg[8], bv[8];
  *(float4*)(gg)     = *(const float4*)(g + lane * 8);
  *(float4*)(gg + 4) = *(const float4*)(g + lane * 8 + 4);
  *(float4*)(bv)     = *(const float4*)(bb + lane * 8);
  *(float4*)(bv + 4) = *(const float4*)(bb + lane * 8 + 4);
  float o[8];
#pragma unroll
  for (int i = 0; i < 8; ++i) o[i] = (v[i] - m) * inv * gg[i] + bv[i];
  if (y) {
    float* yr = y + row * D_ + lane * 8;
    *(float4*)(yr)     = *(float4*)(o);
    *(float4*)(yr + 4) = *(float4*)(o + 4);
  }
  if (yb) {
    __hip_bfloat16 o16[8];
#pragma unroll
    for (int i = 0; i < 8; ++i) o16[i] = __float2bfloat16(o[i]);
    *(uint4*)(yb + row * D_ + lane * 8) = *(uint4*)o16;
  }
}

// ---------------------------------------------------------------- qk prep: Q*0.125 and K/|K| (per head), bf16
__global__ __launch_bounds__(256) void k_prep(const float* __restrict__ qkb,
                                              __hip_bfloat16* __restrict__ qsb,
                                              __hip_bfloat16* __restrict__ knb) {
  int w = threadIdx.x >> 6, lane = threadIdx.x & 63;
  size_t row = (size_t)blockIdx.x * 4 + w;
  const float* xr = qkb + row * D_ + lane * 8;
  float v[8];
  *(float4*)(v)     = *(const float4*)(xr);
  *(float4*)(v + 4) = *(const float4*)(xr + 4);
  float ss = 0.f;
#pragma unroll
  for (int i = 0; i < 8; ++i) ss += v[i] * v[i];
  ss += __shfl_xor(ss, 1); ss += __shfl_xor(ss, 2); ss += __shfl_xor(ss, 4);  // 8-lane head group
  float inv = 1.0f / (sqrtf(ss) + 1e-8f);
  __hip_bfloat16 qo[8], ko[8];
#pragma unroll
  for (int i = 0; i < 8; ++i) {
    qo[i] = __float2bfloat16(v[i] * 0.125f);
    ko[i] = __float2bfloat16(v[i] * inv);
  }
  *(uint4*)(qsb + row * D_ + lane * 8) = *(uint4*)qo;
  *(uint4*)(knb + row * D_ + lane * 8) = *(uint4*)ko;
}

// ---------------------------------------------------------------- fp32 SGEMM (qk projection only)
__global__ __launch_bounds__(256) void k_sgemm(const float* __restrict__ A,
                                               const float* __restrict__ Bm,
                                               float* __restrict__ C,
                                               int N, int K) {
  __shared__ float As[32][128];
  __shared__ float Bs[32][128];
  const int bn0 = blockIdx.x * 128;
  const int bm0 = blockIdx.y * 128;
  const int tid = threadIdx.x;
  const int w = tid >> 6, lane = tid & 63;
  const int wy = w >> 1, wx = w & 1;
  const int ly = lane >> 3, lx = lane & 7;
  const int rm = wy * 64 + ly * 8;
  const int cn = wx * 64 + lx * 8;
  float acc[8][8] = {};

  for (int k0 = 0; k0 < K; k0 += 32) {
#pragma unroll
    for (int ld = 0; ld < 4; ++ld) {
      int f = tid + ld * 256;
      int ar = f >> 3;
      int ac = (f & 7) << 2;
      float4 av = *(const float4*)(A + (size_t)(bm0 + ar) * K + k0 + ac);
      As[ac + 0][ar] = av.x; As[ac + 1][ar] = av.y;
      As[ac + 2][ar] = av.z; As[ac + 3][ar] = av.w;
      int br = f >> 5;
      int bc = (f & 31) << 2;
      *(float4*)(&Bs[br][bc]) = *(const float4*)(Bm + (size_t)(k0 + br) * N + bn0 + bc);
    }
    __syncthreads();
#pragma unroll
    for (int kk = 0; kk < 32; ++kk) {
      float a[8], b[8];
      *(float4*)(a)     = *(const float4*)(&As[kk][rm]);
      *(float4*)(a + 4) = *(const float4*)(&As[kk][rm + 4]);
      *(float4*)(b)     = *(const float4*)(&Bs[kk][cn]);
      *(float4*)(b + 4) = *(const float4*)(&Bs[kk][cn + 4]);
#pragma unroll
      for (int i = 0; i < 8; ++i)
#pragma unroll
        for (int j = 0; j < 8; ++j) acc[i][j] += a[i] * b[j];
    }
    __syncthreads();
  }
#pragma unroll
  for (int i = 0; i < 8; ++i) {
    float* crow = C + (size_t)(bm0 + rm + i) * N + bn0 + cn;
#pragma unroll
    for (int j0 = 0; j0 < 8; j0 += 4)
      *(float4*)(crow + j0) = make_float4(acc[i][j0], acc[i][j0 + 1], acc[i][j0 + 2], acc[i][j0 + 3]);
  }
}

// ---------------------------------------------------------------- bf16 MFMA GEMM
// EPI: 0 C(f32)=AB ; 1 C(f32)+=AB ; 2 C(bf16)=gelu(AB+bias) ; 3 C(f32)+=AB+bias ; 4 C(bf16)=AB
template <int EPI>
__global__ __launch_bounds__(256) void k_bgemm(const __hip_bfloat16* __restrict__ A,
                                               const __hip_bfloat16* __restrict__ BT,
                                               const float* __restrict__ bias,
                                               void* __restrict__ Cv,
                                               int N, int K) {
  __shared__ __align__(16) __hip_bfloat16 As[128 * 32];
  __shared__ __align__(16) __hip_bfloat16 Bs[128 * 32];
  const int bn0 = blockIdx.x * 128;
  const int bm0 = blockIdx.y * 128;
  const int tid = threadIdx.x;
  const int w = tid >> 6, lane = tid & 63;
  const int wy = w >> 1, wx = w & 1;
  const int g = lane >> 4, lr = lane & 15;
  f32x4 acc[4][4] = {};

  const __hip_bfloat16* Abase = A + (size_t)bm0 * K;
  const __hip_bfloat16* Bbase = BT + (size_t)bn0 * K;

  for (int k0 = 0; k0 < K; k0 += 32) {
#pragma unroll
    for (int it = 0; it < 2; ++it) {
      int f = it * 256 + w * 64 + lane;
      int row = f >> 2;
      int kc = ((f & 3) ^ ((row >> 1) & 3)) << 3;
      gload16(Abase + (size_t)row * K + k0 + kc, &As[(it * 256 + w * 64) * 8]);
      gload16(Bbase + (size_t)row * K + k0 + kc, &Bs[(it * 256 + w * 64) * 8]);
    }
    __syncthreads();
    bf16x8 af[4], bfr[4];
#pragma unroll
    for (int m = 0; m < 4; ++m) {
      int row = wy * 64 + m * 16 + lr;
      af[m] = *(const bf16x8*)(&As[row * 32 + ((g ^ ((row >> 1) & 3)) << 3)]);
    }
#pragma unroll
    for (int n = 0; n < 4; ++n) {
      int row = wx * 64 + n * 16 + lr;
      bfr[n] = *(const bf16x8*)(&Bs[row * 32 + ((g ^ ((row >> 1) & 3)) << 3)]);
    }
#pragma unroll
    for (int m = 0; m < 4; ++m)
#pragma unroll
      for (int n = 0; n < 4; ++n)
        acc[m][n] = __builtin_amdgcn_mfma_f32_16x16x32_bf16(af[m], bfr[n], acc[m][n], 0, 0, 0);
    __syncthreads();
  }

  const int colb = bn0 + wx * 64 + lr;
  const int rowb = bm0 + wy * 64 + (g << 2);
#pragma unroll
  for (int m = 0; m < 4; ++m) {
#pragma unroll
    for (int n = 0; n < 4; ++n) {
      int c = colb + n * 16;
      int r0 = rowb + m * 16;
      float bsv = (EPI == 2 || EPI == 3) ? bias[c] : 0.f;
#pragma unroll
      for (int j = 0; j < 4; ++j) {
        float vlu = acc[m][n][j] + bsv;
        size_t idx = (size_t)(r0 + j) * N + c;
        if (EPI == 0) ((float*)Cv)[idx] = vlu;
        else if (EPI == 1) ((float*)Cv)[idx] += vlu;
        else if (EPI == 2) ((__hip_bfloat16*)Cv)[idx] = __float2bfloat16(gelu_f(vlu));
        else if (EPI == 3) ((float*)Cv)[idx] += vlu;
        else ((__hip_bfloat16*)Cv)[idx] = __float2bfloat16(vlu);
      }
    }
  }
}

// ---------------------------------------------------------------- LSH bucket ids
__global__ __launch_bounds__(128) void k_bucket(const float* __restrict__ qk,
                                                const float* __restrict__ rotL,
                                                unsigned char* __restrict__ bkt) {
  int blk = blockIdx.x;
  int tc = blk & 7, h = (blk >> 3) & 7, b = blk >> 6;
  int t0 = tc << 7;
  __shared__ float qs[128][65];
  __shared__ float rs[4096];
  int tid = threadIdx.x;
  for (int f = tid; f < 4096; f += 128) rs[f] = rotL[f];
  const float* base = qk + ((size_t)(b * T_ + t0)) * D_ + h * DH_;
  for (int f = tid; f < 2048; f += 128) {
    int rw = f >> 4, c4 = (f & 15) << 2;
    float4 v = *(const float4*)(base + (size_t)rw * D_ + c4);
    qs[rw][c4] = v.x; qs[rw][c4 + 1] = v.y; qs[rw][c4 + 2] = v.z; qs[rw][c4 + 3] = v.w;
  }
  __syncthreads();
  float s[64];
#pragma unroll
  for (int jr = 0; jr < 64; ++jr) s[jr] = 0.f;
  for (int d = 0; d < 64; ++d) {
    float q = qs[tid][d];
    const float* rp = rs + d * 64;
#pragma unroll
    for (int j4 = 0; j4 < 16; ++j4) {
      float4 rv = *(const float4*)(rp + j4 * 4);
      s[j4 * 4 + 0] += q * rv.x; s[j4 * 4 + 1] += q * rv.y;
      s[j4 * 4 + 2] += q * rv.z; s[j4 * 4 + 3] += q * rv.w;
    }
  }
  int bh = b * H_ + h;
#pragma unroll
  for (int r = 0; r < 8; ++r) {
    float best = s[r * 8];
    int bi = 0;
#pragma unroll
    for (int idx = 1; idx < 16; ++idx) {
      float v = (idx < 8) ? s[r * 8 + idx] : -s[r * 8 + idx - 8];
      if (v > best) { best = v; bi = idx; }
    }
    bkt[((size_t)(bh * NH_ + r)) * T_ + t0 + tid] = (unsigned char)bi;
  }
}

// ---------------------------------------------------------------- stable counting sort + undo
__global__ __launch_bounds__(1024) void k_sort(const unsigned char* __restrict__ bkt,
                                               int* __restrict__ st,
                                               int* __restrict__ undo) {
  int r = blockIdx.x & 7, bh = blockIdx.x >> 3;
  int t = threadIdx.x;
  int bk = bkt[((size_t)(bh * NH_ + r)) * T_ + t];
  int w = t >> 6, lane = t & 63;
  __shared__ int cnt[16][16];
  __shared__ int off[16][16];
  __shared__ int tot[16];
  __shared__ int stt[16];
  unsigned long long below = (1ULL << lane) - 1ULL;
  int myrank = 0;
#pragma unroll
  for (int bb = 0; bb < 16; ++bb) {
    unsigned long long m = __ballot(bk == bb);
    if (bk == bb) myrank = __popcll(m & below);
    if (lane == 0) cnt[w][bb] = __popcll(m);
  }
  __syncthreads();
  if (t < 16) {
    int run = 0;
    for (int ww = 0; ww < 16; ++ww) { off[ww][t] = run; run += cnt[ww][t]; }
    tot[t] = run;
  }
  __syncthreads();
  if (t == 0) {
    int run = 0;
    for (int bb = 0; bb < 16; ++bb) { stt[bb] = run; run += tot[bb]; }
  }
  __syncthreads();
  int pos = stt[bk] + off[w][bk] + myrank;
  st[((size_t)(bh * NH_ + r)) * T_ + pos] = t;
  undo[((size_t)(bh * NH_ + r)) * T_ + t] = pos;
}

// ---------------------------------------------------------------- chunked attention (MFMA, bf16 staged)
// grid (c=128, bh=64); block 256 (4 waves). Inputs pre-scaled/normalized bf16.
__global__ __launch_bounds__(256) void k_attn(const __hip_bfloat16* __restrict__ qs,
                                              const __hip_bfloat16* __restrict__ kn,
                                              const __hip_bfloat16* __restrict__ vv,
                                              const int* __restrict__ st,
                                              __hip_bfloat16* __restrict__ ob,
                                              float* __restrict__ lgb) {
  __shared__ __align__(16) __hip_bfloat16 Kb[128 * 72];
  __shared__ __align__(16) __hip_bfloat16 VbT[64 * 136];   // [d][key], key-octet XOR-swizzled by (d>>3)&3
  __shared__ __align__(16) __hip_bfloat16 PbQb[64 * 136];  // Qb stride 72, then Pb stride 136
  __shared__ int pos[128];

  const int c = blockIdx.x, bh = blockIdx.y;
  const int b = bh >> 3, h = bh & 7;
  const int r = c >> 4;
  const int pc = (c + NC_ - 1) & (NC_ - 1);
  const int tid = threadIdx.x;

  if (tid < 128) {
    int sc = (tid < 64) ? c : pc;
    int slot = ((sc & 15) << 6) + (tid & 63);
    pos[tid] = st[((size_t)(bh * NH_ + (sc >> 4))) * T_ + slot];
  }
  __syncthreads();

  const __hip_bfloat16* qbase = qs + ((size_t)b * T_) * D_ + h * DH_;
  const __hip_bfloat16* kbase = kn + ((size_t)b * T_) * D_ + h * DH_;
  const __hip_bfloat16* vbase = vv + ((size_t)b * T_) * D_ + h * DH_;

  // --- K: 128 rows, 16B/lane
#pragma unroll
  for (int ld = 0; ld < 4; ++ld) {
    int f = ld * 256 + tid;
    int rw = f >> 3, c8 = (f & 7) << 3;
    *(uint4*)(&Kb[rw * 72 + c8]) = *(const uint4*)(kbase + (size_t)pos[rw] * D_ + c8);
  }
  // --- Q: 64 rows
#pragma unroll
  for (int ld = 0; ld < 2; ++ld) {
    int f = ld * 256 + tid;
    int rw = f >> 3, c8 = (f & 7) << 3;
    *(uint4*)(&PbQb[rw * 72 + c8]) = *(const uint4*)(qbase + (size_t)pos[rw] * D_ + c8);
  }
  // --- V: gather bf16 rows, 8x8 register transpose (8 consecutive lanes), b128 stores
  {
    const int w = tid >> 6, rl = tid & 7, d8 = (tid >> 3) & 7;
#pragma unroll
    for (int it = 0; it < 4; ++it) {
      int rw0 = it * 32 + w * 8;
      uint4 x = *(const uint4*)(vbase + (size_t)pos[rw0 + rl] * D_ + d8 * 8);
      unsigned short u[8];
      u[0] = x.x & 0xffff; u[1] = x.x >> 16;
      u[2] = x.y & 0xffff; u[3] = x.y >> 16;
      u[4] = x.z & 0xffff; u[5] = x.z >> 16;
      u[6] = x.w & 0xffff; u[7] = x.w >> 16;
#pragma unroll
      for (int k = 0; k < 3; ++k) {
        const int xm = 1 << k;
        const bool sel = (rl >> k) & 1;
#pragma unroll
        for (int j0 = 0; j0 < 8; ++j0) {
          if ((j0 >> k) & 1) continue;
          int j1 = j0 | (1 << k);
          unsigned int send = sel ? (unsigned int)u[j0] : (unsigned int)u[j1];
          unsigned int recv = (unsigned int)__shfl_xor((int)send, xm);
          if (sel) u[j0] = (unsigned short)recv; else u[j1] = (unsigned short)recv;
        }
      }
      int d = d8 * 8 + rl;
      uint4 y;
      y.x = (unsigned int)u[0] | ((unsigned int)u[1] << 16);
      y.y = (unsigned int)u[2] | ((unsigned int)u[3] << 16);
      y.z = (unsigned int)u[4] | ((unsigned int)u[5] << 16);
      y.w = (unsigned int)u[6] | ((unsigned int)u[7] << 16);
      *(uint4*)(&VbT[d * 136 + (rw0 ^ (((d >> 3) & 3) << 3))]) = y;
    }
  }
  __syncthreads();

  const int w = tid >> 6, lane = tid & 63;
  const int g = lane >> 4, l15 = lane & 15;
  const int q0 = w * 16;

  // --- dots: wave w computes q rows q0..q0+15 x all 128 keys
  bf16x8 af0 = *(const bf16x8*)(&PbQb[(q0 + l15) * 72 + g * 8]);
  bf16x8 af1 = *(const bf16x8*)(&PbQb[(q0 + l15) * 72 + 32 + g * 8]);
  f32x4 dacc[8];
#pragma unroll
  for (int n = 0; n < 8; ++n) dacc[n] = (f32x4){0.f, 0.f, 0.f, 0.f};
#pragma unroll
  for (int n = 0; n < 8; ++n) {
    bf16x8 b0 = *(const bf16x8*)(&Kb[(n * 16 + l15) * 72 + g * 8]);
    bf16x8 b1 = *(const bf16x8*)(&Kb[(n * 16 + l15) * 72 + 32 + g * 8]);
    dacc[n] = __builtin_amdgcn_mfma_f32_16x16x32_bf16(af0, b0, dacc[n], 0, 0, 0);
    dacc[n] = __builtin_amdgcn_mfma_f32_16x16x32_bf16(af1, b1, dacc[n], 0, 0, 0);
  }
  __syncthreads();   // Qb reads done before Pb overwrites

  // --- mask + softmax (fp32, fast exp/log)
  int qpos[4], kpos[8];
#pragma unroll
  for (int reg = 0; reg < 4; ++reg) qpos[reg] = pos[q0 + g * 4 + reg];
#pragma unroll
  for (int n = 0; n < 8; ++n) kpos[n] = pos[n * 16 + l15];
  float pr[8][4];
  float lgt[4];
#pragma unroll
  for (int reg = 0; reg < 4; ++reg) {
    float mx = -3.0e38f;
#pragma unroll
    for (int n = 0; n < 8; ++n) {
      float dv = dacc[n][reg];
      dv = (kpos[n] == qpos[reg]) ? -5.0e4f : dv;
      pr[n][reg] = dv;
      mx = fmaxf(mx, dv);
    }
    mx = fmaxf(mx, __shfl_xor(mx, 1));
    mx = fmaxf(mx, __shfl_xor(mx, 2));
    mx = fmaxf(mx, __shfl_xor(mx, 4));
    mx = fmaxf(mx, __shfl_xor(mx, 8));
    float s = 0.f;
#pragma unroll
    for (int n = 0; n < 8; ++n) { float e = __expf(pr[n][reg] - mx); pr[n][reg] = e; s += e; }
    s += __shfl_xor(s, 1); s += __shfl_xor(s, 2);
    s += __shfl_xor(s, 4); s += __shfl_xor(s, 8);
    lgt[reg] = mx + __logf(s);
    float isc = 1.0f / s;
#pragma unroll
    for (int n = 0; n < 8; ++n) pr[n][reg] *= isc;
  }
#pragma unroll
  for (int n = 0; n < 8; ++n)
#pragma unroll
    for (int reg = 0; reg < 4; ++reg)
      PbQb[(q0 + g * 4 + reg) * 136 + n * 16 + l15] = __float2bfloat16(pr[n][reg]);
  const size_t slotbase = ((size_t)(bh * NH_ + r)) * T_ + ((c & 15) << 6);
  if (l15 == 0) {
#pragma unroll
    for (int reg = 0; reg < 4; ++reg)
      lgb[slotbase + q0 + g * 4 + reg] = lgt[reg];
  }
  __syncthreads();

  // --- PV: wave w computes O^T rows d=16w..16w+15 x all 64 q
  bf16x8 va[4];
#pragma unroll
  for (int s = 0; s < 4; ++s) {
    int dd = w * 16 + l15;
    va[s] = *(const bf16x8*)(&VbT[dd * 136 + ((s * 32 + g * 8) ^ (((dd >> 3) & 3) << 3))]);
  }
#pragma unroll
  for (int n = 0; n < 4; ++n) {
    f32x4 oa = (f32x4){0.f, 0.f, 0.f, 0.f};
#pragma unroll
    for (int s = 0; s < 4; ++s) {
      bf16x8 pb = *(const bf16x8*)(&PbQb[(n * 16 + l15) * 136 + s * 32 + g * 8]);
      oa = __builtin_amdgcn_mfma_f32_16x16x32_bf16(va[s], pb, oa, 0, 0, 0);
    }
    int q = n * 16 + l15;
    int d = w * 16 + g * 4;
    __hip_bfloat16 o4[4];
#pragma unroll
    for (int reg = 0; reg < 4; ++reg) o4[reg] = __float2bfloat16(oa[reg]);
    *(uint2*)(&ob[(slotbase + q) * DH_ + d]) = *(uint2*)o4;
  }
}

// ---------------------------------------------------------------- round combine (gather via undo)
__global__ __launch_bounds__(256) void k_combine(const __hip_bfloat16* __restrict__ ob,
                                                 const float* __restrict__ lgb,
                                                 const int* __restrict__ undo,
                                                 __hip_bfloat16* __restrict__ attnb) {
  int g = threadIdx.x >> 6, lane = threadIdx.x & 63;
  int idx = blockIdx.x * 4 + g;
  int bh = idx >> 10, t = idx & (T_ - 1);
  int b = bh >> 3, h = bh & 7;
  int su[8];
  float lg[8];
  float m = -3.0e38f;
#pragma unroll
  for (int r = 0; r < 8; ++r) {
    su[r] = undo[((size_t)(bh * NH_ + r)) * T_ + t];
    lg[r] = lgb[((size_t)(bh * NH_ + r)) * T_ + su[r]];
    m = fmaxf(m, lg[r]);
  }
  float s = 0.f;
#pragma unroll
  for (int r = 0; r < 8; ++r) { lg[r] = __expf(lg[r] - m); s += lg[r]; }
  float invs = 1.0f / s;
  float o = 0.f;
#pragma unroll
  for (int r = 0; r < 8; ++r)
    o += lg[r] * invs * __bfloat162float(ob[(((size_t)(bh * NH_ + r)) * T_ + su[r]) * DH_ + lane]);
  attnb[((size_t)(b * T_ + t)) * D_ + h * DH_ + lane] = __float2bfloat16(o);
}

// ---------------------------------------------------------------- final reduction
__global__ void k_zero(float* __restrict__ p, int n) {
  int i = blockIdx.x * blockDim.x + threadIdx.x;
  if (i < n) p[i] = 0.f;
}

__global__ __launch_bounds__(256) void k_colsum(const float* __restrict__ xn,
                                                float* __restrict__ mean) {
  int b = blockIdx.x, dc = blockIdx.y, tc = blockIdx.z;
  int d = dc * 256 + threadIdx.x;
  float s = 0.f;
  for (int tt = 0; tt < 64; ++tt) {
    int t = tc * 64 + tt;
    s += xn[((size_t)(b * T_ + t)) * D_ + d];
  }
  atomicAdd(&mean[b * D_ + d], s);
}

__global__ __launch_bounds__(512) void k_fc(const float* __restrict__ mean,
                                            const float* __restrict__ Wfc,
                                            float* __restrict__ out) {
  int b = blockIdx.x, n = threadIdx.x;
  __shared__ float ms[512];
  ms[n] = mean[b * D_ + n] * (1.0f / 1024.0f);
  __syncthreads();
  float acc = 0.f;
  for (int d = 0; d < 512; ++d) acc += ms[d] * Wfc[(size_t)d * D_ + n];
  out[b * D_ + n] = acc;
}

// ---------------------------------------------------------------- launcher
extern "C" void kernel_launch(void* const* d_in, const int* in_sizes, int n_in,
                              void* d_out, int out_size, void* d_ws, size_t ws_size,
                              hipStream_t stream) {
  (void)in_sizes; (void)n_in; (void)out_size; (void)ws_size;
  const int*   ids  = (const int*)d_in[0];
  const float* te   = (const float*)d_in[1];
  const float* pe   = (const float*)d_in[2];
  const float* lag  = (const float*)d_in[3];
  const float* lab  = (const float*)d_in[4];
  const float* Wqk  = (const float*)d_in[5];
  const float* Wv   = (const float*)d_in[6];
  const float* Wo   = (const float*)d_in[7];
  const float* lfg  = (const float*)d_in[8];
  const float* lfb  = (const float*)d_in[9];
  const float* W1   = (const float*)d_in[10];
  const float* b1   = (const float*)d_in[11];
  const float* W2   = (const float*)d_in[12];
  const float* b2   = (const float*)d_in[13];
  const float* lnfg = (const float*)d_in[14];
  const float* lnfb = (const float*)d_in[15];
  const float* Wfc  = (const float*)d_in[16];
  const float* rot  = (const float*)d_in[17];

  char* ws = (char*)d_ws;
  size_t off = 0;
  auto carve = [&](size_t bytes) -> void* {
    void* p = ws + off;
    off += (bytes + 255) & ~(size_t)255;
    return p;
  };
  float* x1    = (float*)carve((size_t)ROWS_ * D_ * 4);
  float* x2    = (float*)carve((size_t)ROWS_ * D_ * 4);
  float* xn    = (float*)carve((size_t)ROWS_ * D_ * 4);
  float* qkb   = (float*)carve((size_t)ROWS_ * D_ * 4);
  __hip_bfloat16* vvb   = (__hip_bfloat16*)carve((size_t)ROWS_ * D_ * 2);
  __hip_bfloat16* qsb   = (__hip_bfloat16*)carve((size_t)ROWS_ * D_ * 2);
  __hip_bfloat16* knb   = (__hip_bfloat16*)carve((size_t)ROWS_ * D_ * 2);
  __hip_bfloat16* xnb   = (__hip_bfloat16*)carve((size_t)ROWS_ * D_ * 2);
  __hip_bfloat16* attnb = (__hip_bfloat16*)carve((size_t)ROWS_ * D_ * 2);
  __hip_bfloat16* ob    = (__hip_bfloat16*)carve((size_t)BH_ * NH_ * T_ * DH_ * 2);  // 67 MB
  __hip_bfloat16* hid   = ob;  // alias: ob dead after combine; hid needs 32 MB
  unsigned char* bkt = (unsigned char*)carve((size_t)BH_ * NH_ * T_);
  int*   stb   = (int*)carve((size_t)BH_ * NH_ * T_ * 4);
  int*   undo  = (int*)carve((size_t)BH_ * NH_ * T_ * 4);
  float* lgb   = (float*)carve((size_t)BH_ * NH_ * T_ * 4);
  float* meanb = (float*)carve((size_t)B_ * D_ * 4);
  __hip_bfloat16* WvT = (__hip_bfloat16*)carve((size_t)DEPTH_ * D_ * D_ * 2);
  __hip_bfloat16* WoT = (__hip_bfloat16*)carve((size_t)DEPTH_ * D_ * D_ * 2);
  __hip_bfloat16* W1T = (__hip_bfloat16*)carve((size_t)DEPTH_ * D_ * FF_ * 2);
  __hip_bfloat16* W2T = (__hip_bfloat16*)carve((size_t)DEPTH_ * FF_ * D_ * 2);

  k_wt<<<dim3(D_ / 32, D_ / 32, DEPTH_), 256, 0, stream>>>(Wv, WvT, D_, D_);
  k_wt<<<dim3(D_ / 32, D_ / 32, DEPTH_), 256, 0, stream>>>(Wo, WoT, D_, D_);
  k_wt<<<dim3(FF_ / 32, D_ / 32, DEPTH_), 256, 0, stream>>>(W1, W1T, D_, FF_);
  k_wt<<<dim3(D_ / 32, FF_ / 32, DEPTH_), 256, 0, stream>>>(W2, W2T, FF_, D_);

  k_embed<<<ROWS_, 128, 0, stream>>>(ids, te, pe, x1, x2);

  for (int l = 0; l < DEPTH_; ++l) {
    const float* wqk = Wqk + (size_t)l * D_ * D_;
    const __hip_bfloat16* wvt = WvT + (size_t)l * D_ * D_;
    const __hip_bfloat16* wot = WoT + (size_t)l * D_ * D_;
    const __hip_bfloat16* w1t = W1T + (size_t)l * D_ * FF_;
    const __hip_bfloat16* w2t = W2T + (size_t)l * FF_ * D_;

    k_ln<<<ROWS_ / 4, 256, 0, stream>>>(x2, nullptr, lag + l * D_, lab + l * D_, xn, xnb);
    k_sgemm<<<dim3(D_ / 128, ROWS_ / 128), 256, 0, stream>>>(xn, wqk, qkb, D_, D_);
    k_bgemm<4><<<dim3(D_ / 128, ROWS_ / 128), 256, 0, stream>>>(xnb, wvt, nullptr, vvb, D_, D_);
    k_prep<<<ROWS_ / 4, 256, 0, stream>>>(qkb, qsb, knb);
    k_bucket<<<512, 128, 0, stream>>>(qkb, rot + (size_t)l * 4096, bkt);
    k_sort<<<512, 1024, 0, stream>>>(bkt, stb, undo);
    k_attn<<<dim3(NC_, BH_), 256, 0, stream>>>(qsb, knb, vvb, stb, ob, lgb);
    k_combine<<<BH_ * T_ / 4, 256, 0, stream>>>(ob, lgb, undo, attnb);
    k_bgemm<1><<<dim3(D_ / 128, ROWS_ / 128), 256, 0, stream>>>(attnb, wot, nullptr, x1, D_, D_);

    k_ln<<<ROWS_ / 4, 256, 0, stream>>>(x1, nullptr, lfg + l * D_, lfb + l * D_, nullptr, xnb);
    k_bgemm<2><<<dim3(FF_ / 128, ROWS_ / 128), 256, 0, stream>>>(xnb, w1t, b1 + l * FF_, hid, FF_, D_);
    k_bgemm<3><<<dim3(D_ / 128, ROWS_ / 128), 256, 0, stream>>>(hid, w2t, b2 + l * D_, x2, D_, FF_);
  }

  k_ln<<<ROWS_ / 4, 256, 0, stream>>>(x1, x2, lnfg, lnfb, xn, nullptr);
  k_zero<<<16, 256, 0, stream>>>(meanb, B_ * D_);
  k_colsum<<<dim3(B_, 2, 16), 256, 0, stream>>>(xn, meanb);
  k_fc<<<B_, 512, 0, stream>>>(meanb, Wfc, (float*)d_out);
}

// Round 9
// 3199.090 us; speedup vs baseline: 3.0218x; 1.0003x over previous
//
#include <hip/hip_runtime.h>
#include <hip/hip_bf16.h>
#include <cstdint>
#include <cstddef>

#define B_ 8
#define T_ 1024
#define D_ 512
#define H_ 8
#define DH_ 64
#define DEPTH_ 8
#define FF_ 2048
#define NH_ 8
#define BS_ 64
#define NB_ 16
#define NC_ 128
#define BH_ 64
#define ROWS_ 8192   // B*T

typedef __attribute__((ext_vector_type(8))) short bf16x8;
typedef __attribute__((ext_vector_type(4))) float f32x4;

typedef __attribute__((address_space(1))) const unsigned int g_u32;
typedef __attribute__((address_space(3))) unsigned int l_u32;
__device__ __forceinline__ void gload16(const void* g, void* l) {
  __builtin_amdgcn_global_load_lds((g_u32*)g, (l_u32*)l, 16, 0, 0);
}

// ---------------------------------------------------------------- utilities
__device__ __forceinline__ float wave_sum(float v) {
#pragma unroll
  for (int o = 1; o < 64; o <<= 1) v += __shfl_xor(v, o);
  return v;
}

__device__ __forceinline__ float gelu_f(float u) {
  float c = u + 0.044715f * u * u * u;
  float t = tanhf(0.7978845608028654f * c);
  return 0.5f * u * (1.0f + t);
}

// ---------------------------------------------------------------- embedding
__global__ __launch_bounds__(128) void k_embed(const int* __restrict__ ids,
                                               const float* __restrict__ te,
                                               const float* __restrict__ pe,
                                               float* __restrict__ x1,
                                               float* __restrict__ x2) {
  int bt = blockIdx.x;
  int t = bt & (T_ - 1);
  int d = threadIdx.x * 4;
  int id = ids[bt];
  float4 v = *(const float4*)(te + (size_t)id * D_ + d);
  float4 p = *(const float4*)(pe + (size_t)t * D_ + d);
  v.x += p.x; v.y += p.y; v.z += p.z; v.w += p.w;
  *(float4*)(x1 + (size_t)bt * D_ + d) = v;
  *(float4*)(x2 + (size_t)bt * D_ + d) = v;
}

// ---------------------------------------------------------------- weight transpose + bf16
__global__ __launch_bounds__(256) void k_wt(const float* __restrict__ W,
                                            __hip_bfloat16* __restrict__ WT,
                                            int K, int N) {
  const float* Wl = W + (size_t)blockIdx.z * K * N;
  __hip_bfloat16* WTl = WT + (size_t)blockIdx.z * K * N;
  __shared__ float tile[32][33];
  int n0 = blockIdx.x * 32, k0 = blockIdx.y * 32;
  int tx = threadIdx.x & 31, ty = threadIdx.x >> 5;  // 32 x 8
#pragma unroll
  for (int i = 0; i < 32; i += 8)
    tile[ty + i][tx] = Wl[(size_t)(k0 + ty + i) * N + n0 + tx];
  __syncthreads();
#pragma unroll
  for (int i = 0; i < 32; i += 8)
    WTl[(size_t)(n0 + ty + i) * K + k0 + tx] = __float2bfloat16(tile[tx][ty + i]);
}

// ---------------------------------------------------------------- weight transpose + hi/lo bf16 split
__global__ __launch_bounds__(256) void k_wt2(const float* __restrict__ W,
                                             __hip_bfloat16* __restrict__ WhT,
                                             __hip_bfloat16* __restrict__ WlT,
                                             int K, int N) {
  const float* Wl = W + (size_t)blockIdx.z * K * N;
  __hip_bfloat16* WhTl = WhT + (size_t)blockIdx.z * K * N;
  __hip_bfloat16* WlTl = WlT + (size_t)blockIdx.z * K * N;
  __shared__ float tile[32][33];
  int n0 = blockIdx.x * 32, k0 = blockIdx.y * 32;
  int tx = threadIdx.x & 31, ty = threadIdx.x >> 5;
#pragma unroll
  for (int i = 0; i < 32; i += 8)
    tile[ty + i][tx] = Wl[(size_t)(k0 + ty + i) * N + n0 + tx];
  __syncthreads();
#pragma unroll
  for (int i = 0; i < 32; i += 8) {
    float v = tile[tx][ty + i];
    __hip_bfloat16 hi = __float2bfloat16(v);
    float lo = v - __bfloat162float(hi);
    size_t idx = (size_t)(n0 + ty + i) * K + k0 + tx;
    WhTl[idx] = hi;
    WlTl[idx] = __float2bfloat16(lo);
  }
}

// ---------------------------------------------------------------- layernorm
// yb = bf16(out), ylo = bf16(out - yb) (split residual); all outputs nullable
__global__ __launch_bounds__(256) void k_ln(const float* __restrict__ x,
                                            const float* __restrict__ xb,
                                            const float* __restrict__ g,
                                            const float* __restrict__ bb,
                                            float* __restrict__ y,
                                            __hip_bfloat16* __restrict__ yb,
                                            __hip_bfloat16* __restrict__ ylo) {
  int w = threadIdx.x >> 6, lane = threadIdx.x & 63;
  size_t row = (size_t)blockIdx.x * 4 + w;
  const float* xr = x + row * D_ + lane * 8;
  float v[8];
  *(float4*)(v)     = *(const float4*)(xr);
  *(float4*)(v + 4) = *(const float4*)(xr + 4);
  if (xb) {
    const float* x2r = xb + row * D_ + lane * 8;
    float u[8];
    *(float4*)(u)     = *(const float4*)(x2r);
    *(float4*)(u + 4) = *(const float4*)(x2r + 4);
#pragma unroll
    for (int i = 0; i < 8; ++i) v[i] = 0.5f * (v[i] + u[i]);
  }
  float s = 0.f;
#pragma unroll
  for (int i = 0; i < 8; ++i) s += v[i];
  s = wave_sum(s);
  float m = s * (1.0f / D_);
  float q = 0.f;
#pragma unroll
  for (int i = 0; i < 8; ++i) { float d = v[i] - m; q += d * d; }
  q = wave_sum(q);
  float inv = 1.0f / sqrtf(q * (1.0f / D_) + 1e-5f);
  float gg[8], bv[8];
  *(float4*)(gg)     = *(const float4*)(g + lane * 8);
  *(float4*)(gg + 4) = *(const float4*)(g + lane * 8 + 4);
  *(float4*)(bv)     = *(const float4*)(bb + lane * 8);
  *(float4*)(bv + 4) = *(const float4*)(bb + lane * 8 + 4);
  float o[8];
#pragma unroll
  for (int i = 0; i < 8; ++i) o[i] = (v[i] - m) * inv * gg[i] + bv[i];
  if (y) {
    float* yr = y + row * D_ + lane * 8;
    *(float4*)(yr)     = *(float4*)(o);
    *(float4*)(yr + 4) = *(float4*)(o + 4);
  }
  if (yb) {
    __hip_bfloat16 o16[8];
#pragma unroll
    for (int i = 0; i < 8; ++i) o16[i] = __float2bfloat16(o[i]);
    *(uint4*)(yb + row * D_ + lane * 8) = *(uint4*)o16;
    if (ylo) {
      __hip_bfloat16 l16[8];
#pragma unroll
      for (int i = 0; i < 8; ++i)
        l16[i] = __float2bfloat16(o[i] - __bfloat162float(o16[i]));
      *(uint4*)(ylo + row * D_ + lane * 8) = *(uint4*)l16;
    }
  }
}

// ---------------------------------------------------------------- split-bf16 MFMA GEMM (qk projection)
// C(f32) = (Ah+Al) x (Bh+Bl)^T  ~=  Ah.Bh + Ah.Bl + Al.Bh   (error ~2^-18 rel)
__global__ __launch_bounds__(256) void k_qgemm(const __hip_bfloat16* __restrict__ Ah,
                                               const __hip_bfloat16* __restrict__ Al,
                                               const __hip_bfloat16* __restrict__ BhT,
                                               const __hip_bfloat16* __restrict__ BlT,
                                               float* __restrict__ C, int N, int K) {
  __shared__ __align__(16) __hip_bfloat16 Ash[128 * 32];
  __shared__ __align__(16) __hip_bfloat16 Asl[128 * 32];
  __shared__ __align__(16) __hip_bfloat16 Bsh[128 * 32];
  __shared__ __align__(16) __hip_bfloat16 Bsl[128 * 32];
  const int bn0 = blockIdx.x * 128;
  const int bm0 = blockIdx.y * 128;
  const int tid = threadIdx.x;
  const int w = tid >> 6, lane = tid & 63;
  const int wy = w >> 1, wx = w & 1;
  const int g = lane >> 4, lr = lane & 15;
  f32x4 acc[4][4] = {};
  const size_t aoff = (size_t)bm0 * K;
  const size_t boff = (size_t)bn0 * K;

  for (int k0 = 0; k0 < K; k0 += 32) {
#pragma unroll
    for (int it = 0; it < 2; ++it) {
      int f = it * 256 + w * 64 + lane;
      int row = f >> 2;
      int kc = ((f & 3) ^ ((row >> 1) & 3)) << 3;
      size_t ga = aoff + (size_t)row * K + k0 + kc;
      size_t gb = boff + (size_t)row * K + k0 + kc;
      int lo = (it * 256 + w * 64) * 8;
      gload16(Ah + ga, &Ash[lo]);
      gload16(Al + ga, &Asl[lo]);
      gload16(BhT + gb, &Bsh[lo]);
      gload16(BlT + gb, &Bsl[lo]);
    }
    __syncthreads();
    bf16x8 ah[4], al[4], bh[4], bl[4];
#pragma unroll
    for (int m = 0; m < 4; ++m) {
      int row = wy * 64 + m * 16 + lr;
      int o = row * 32 + ((g ^ ((row >> 1) & 3)) << 3);
      ah[m] = *(const bf16x8*)(&Ash[o]);
      al[m] = *(const bf16x8*)(&Asl[o]);
    }
#pragma unroll
    for (int n = 0; n < 4; ++n) {
      int row = wx * 64 + n * 16 + lr;
      int o = row * 32 + ((g ^ ((row >> 1) & 3)) << 3);
      bh[n] = *(const bf16x8*)(&Bsh[o]);
      bl[n] = *(const bf16x8*)(&Bsl[o]);
    }
#pragma unroll
    for (int m = 0; m < 4; ++m)
#pragma unroll
      for (int n = 0; n < 4; ++n) {
        acc[m][n] = __builtin_amdgcn_mfma_f32_16x16x32_bf16(ah[m], bh[n], acc[m][n], 0, 0, 0);
        acc[m][n] = __builtin_amdgcn_mfma_f32_16x16x32_bf16(ah[m], bl[n], acc[m][n], 0, 0, 0);
        acc[m][n] = __builtin_amdgcn_mfma_f32_16x16x32_bf16(al[m], bh[n], acc[m][n], 0, 0, 0);
      }
    __syncthreads();
  }

  const int colb = bn0 + wx * 64 + lr;
  const int rowb = bm0 + wy * 64 + (g << 2);
#pragma unroll
  for (int m = 0; m < 4; ++m)
#pragma unroll
    for (int n = 0; n < 4; ++n) {
      int c = colb + n * 16;
      int r0 = rowb + m * 16;
#pragma unroll
      for (int j = 0; j < 4; ++j)
        C[(size_t)(r0 + j) * N + c] = acc[m][n][j];
    }
}

// ---------------------------------------------------------------- qk prep: Q*0.125 and K/|K| (per head), bf16
__global__ __launch_bounds__(256) void k_prep(const float* __restrict__ qkb,
                                              __hip_bfloat16* __restrict__ qsb,
                                              __hip_bfloat16* __restrict__ knb) {
  int w = threadIdx.x >> 6, lane = threadIdx.x & 63;
  size_t row = (size_t)blockIdx.x * 4 + w;
  const float* xr = qkb + row * D_ + lane * 8;
  float v[8];
  *(float4*)(v)     = *(const float4*)(xr);
  *(float4*)(v + 4) = *(const float4*)(xr + 4);
  float ss = 0.f;
#pragma unroll
  for (int i = 0; i < 8; ++i) ss += v[i] * v[i];
  ss += __shfl_xor(ss, 1); ss += __shfl_xor(ss, 2); ss += __shfl_xor(ss, 4);
  float inv = 1.0f / (sqrtf(ss) + 1e-8f);
  __hip_bfloat16 qo[8], ko[8];
#pragma unroll
  for (int i = 0; i < 8; ++i) {
    qo[i] = __float2bfloat16(v[i] * 0.125f);
    ko[i] = __float2bfloat16(v[i] * inv);
  }
  *(uint4*)(qsb + row * D_ + lane * 8) = *(uint4*)qo;
  *(uint4*)(knb + row * D_ + lane * 8) = *(uint4*)ko;
}

// ---------------------------------------------------------------- bf16 MFMA GEMM
// EPI: 0 C(f32)=AB ; 1 C(f32)+=AB ; 2 C(bf16)=gelu(AB+bias) ; 3 C(f32)+=AB+bias ; 4 C(bf16)=AB
template <int EPI>
__global__ __launch_bounds__(256) void k_bgemm(const __hip_bfloat16* __restrict__ A,
                                               const __hip_bfloat16* __restrict__ BT,
                                               const float* __restrict__ bias,
                                               void* __restrict__ Cv,
                                               int N, int K) {
  __shared__ __align__(16) __hip_bfloat16 As[128 * 32];
  __shared__ __align__(16) __hip_bfloat16 Bs[128 * 32];
  const int bn0 = blockIdx.x * 128;
  const int bm0 = blockIdx.y * 128;
  const int tid = threadIdx.x;
  const int w = tid >> 6, lane = tid & 63;
  const int wy = w >> 1, wx = w & 1;
  const int g = lane >> 4, lr = lane & 15;
  f32x4 acc[4][4] = {};

  const __hip_bfloat16* Abase = A + (size_t)bm0 * K;
  const __hip_bfloat16* Bbase = BT + (size_t)bn0 * K;

  for (int k0 = 0; k0 < K; k0 += 32) {
#pragma unroll
    for (int it = 0; it < 2; ++it) {
      int f = it * 256 + w * 64 + lane;
      int row = f >> 2;
      int kc = ((f & 3) ^ ((row >> 1) & 3)) << 3;
      gload16(Abase + (size_t)row * K + k0 + kc, &As[(it * 256 + w * 64) * 8]);
      gload16(Bbase + (size_t)row * K + k0 + kc, &Bs[(it * 256 + w * 64) * 8]);
    }
    __syncthreads();
    bf16x8 af[4], bfr[4];
#pragma unroll
    for (int m = 0; m < 4; ++m) {
      int row = wy * 64 + m * 16 + lr;
      af[m] = *(const bf16x8*)(&As[row * 32 + ((g ^ ((row >> 1) & 3)) << 3)]);
    }
#pragma unroll
    for (int n = 0; n < 4; ++n) {
      int row = wx * 64 + n * 16 + lr;
      bfr[n] = *(const bf16x8*)(&Bs[row * 32 + ((g ^ ((row >> 1) & 3)) << 3)]);
    }
#pragma unroll
    for (int m = 0; m < 4; ++m)
#pragma unroll
      for (int n = 0; n < 4; ++n)
        acc[m][n] = __builtin_amdgcn_mfma_f32_16x16x32_bf16(af[m], bfr[n], acc[m][n], 0, 0, 0);
    __syncthreads();
  }

  const int colb = bn0 + wx * 64 + lr;
  const int rowb = bm0 + wy * 64 + (g << 2);
#pragma unroll
  for (int m = 0; m < 4; ++m) {
#pragma unroll
    for (int n = 0; n < 4; ++n) {
      int c = colb + n * 16;
      int r0 = rowb + m * 16;
      float bsv = (EPI == 2 || EPI == 3) ? bias[c] : 0.f;
#pragma unroll
      for (int j = 0; j < 4; ++j) {
        float vlu = acc[m][n][j] + bsv;
        size_t idx = (size_t)(r0 + j) * N + c;
        if (EPI == 0) ((float*)Cv)[idx] = vlu;
        else if (EPI == 1) ((float*)Cv)[idx] += vlu;
        else if (EPI == 2) ((__hip_bfloat16*)Cv)[idx] = __float2bfloat16(gelu_f(vlu));
        else if (EPI == 3) ((float*)Cv)[idx] += vlu;
        else ((__hip_bfloat16*)Cv)[idx] = __float2bfloat16(vlu);
      }
    }
  }
}

// ---------------------------------------------------------------- LSH bucket ids
__global__ __launch_bounds__(128) void k_bucket(const float* __restrict__ qk,
                                                const float* __restrict__ rotL,
                                                unsigned char* __restrict__ bkt) {
  int blk = blockIdx.x;
  int tc = blk & 7, h = (blk >> 3) & 7, b = blk >> 6;
  int t0 = tc << 7;
  __shared__ float qs[128][65];
  __shared__ float rs[4096];
  int tid = threadIdx.x;
  for (int f = tid; f < 4096; f += 128) rs[f] = rotL[f];
  const float* base = qk + ((size_t)(b * T_ + t0)) * D_ + h * DH_;
  for (int f = tid; f < 2048; f += 128) {
    int rw = f >> 4, c4 = (f & 15) << 2;
    float4 v = *(const float4*)(base + (size_t)rw * D_ + c4);
    qs[rw][c4] = v.x; qs[rw][c4 + 1] = v.y; qs[rw][c4 + 2] = v.z; qs[rw][c4 + 3] = v.w;
  }
  __syncthreads();
  float s[64];
#pragma unroll
  for (int jr = 0; jr < 64; ++jr) s[jr] = 0.f;
  for (int d = 0; d < 64; ++d) {
    float q = qs[tid][d];
    const float* rp = rs + d * 64;
#pragma unroll
    for (int j4 = 0; j4 < 16; ++j4) {
      float4 rv = *(const float4*)(rp + j4 * 4);
      s[j4 * 4 + 0] += q * rv.x; s[j4 * 4 + 1] += q * rv.y;
      s[j4 * 4 + 2] += q * rv.z; s[j4 * 4 + 3] += q * rv.w;
    }
  }
  int bh = b * H_ + h;
#pragma unroll
  for (int r = 0; r < 8; ++r) {
    float best = s[r * 8];
    int bi = 0;
#pragma unroll
    for (int idx = 1; idx < 16; ++idx) {
      float v = (idx < 8) ? s[r * 8 + idx] : -s[r * 8 + idx - 8];
      if (v > best) { best = v; bi = idx; }
    }
    bkt[((size_t)(bh * NH_ + r)) * T_ + t0 + tid] = (unsigned char)bi;
  }
}

// ---------------------------------------------------------------- stable counting sort + undo
__global__ __launch_bounds__(1024) void k_sort(const unsigned char* __restrict__ bkt,
                                               int* __restrict__ st,
                                               int* __restrict__ undo) {
  int r = blockIdx.x & 7, bh = blockIdx.x >> 3;
  int t = threadIdx.x;
  int bk = bkt[((size_t)(bh * NH_ + r)) * T_ + t];
  int w = t >> 6, lane = t & 63;
  __shared__ int cnt[16][16];
  __shared__ int off[16][16];
  __shared__ int tot[16];
  __shared__ int stt[16];
  unsigned long long below = (1ULL << lane) - 1ULL;
  int myrank = 0;
#pragma unroll
  for (int bb = 0; bb < 16; ++bb) {
    unsigned long long m = __ballot(bk == bb);
    if (bk == bb) myrank = __popcll(m & below);
    if (lane == 0) cnt[w][bb] = __popcll(m);
  }
  __syncthreads();
  if (t < 16) {
    int run = 0;
    for (int ww = 0; ww < 16; ++ww) { off[ww][t] = run; run += cnt[ww][t]; }
    tot[t] = run;
  }
  __syncthreads();
  if (t == 0) {
    int run = 0;
    for (int bb = 0; bb < 16; ++bb) { stt[bb] = run; run += tot[bb]; }
  }
  __syncthreads();
  int pos = stt[bk] + off[w][bk] + myrank;
  st[((size_t)(bh * NH_ + r)) * T_ + pos] = t;
  undo[((size_t)(bh * NH_ + r)) * T_ + t] = pos;
}

// ---------------------------------------------------------------- chunked attention (MFMA, bf16 staged)
// grid (c=128, bh=64); block 256 (4 waves). No max pass (dots bounded, masked -5e4 underflows
// to 0); P stored unnormalized, 1/s applied at the PV epilogue via lsb[].
__global__ __launch_bounds__(256) void k_attn(const __hip_bfloat16* __restrict__ qs,
                                              const __hip_bfloat16* __restrict__ kn,
                                              const __hip_bfloat16* __restrict__ vv,
                                              const int* __restrict__ st,
                                              __hip_bfloat16* __restrict__ ob,
                                              float* __restrict__ lgb) {
  __shared__ __align__(16) __hip_bfloat16 Kb[128 * 72];
  __shared__ __align__(16) __hip_bfloat16 VbT[64 * 136];   // [d][key], key-octet XOR-swizzled by (d>>3)&3
  __shared__ __align__(16) __hip_bfloat16 PbQb[64 * 136];  // Qb stride 72, then Pb stride 136
  __shared__ float lsb[64];
  __shared__ int pos[128];

  const int c = blockIdx.x, bh = blockIdx.y;
  const int b = bh >> 3, h = bh & 7;
  const int r = c >> 4;
  const int pc = (c + NC_ - 1) & (NC_ - 1);
  const int tid = threadIdx.x;

  if (tid < 128) {
    int sc = (tid < 64) ? c : pc;
    int slot = ((sc & 15) << 6) + (tid & 63);
    pos[tid] = st[((size_t)(bh * NH_ + (sc >> 4))) * T_ + slot];
  }
  __syncthreads();

  const __hip_bfloat16* qbase = qs + ((size_t)b * T_) * D_ + h * DH_;
  const __hip_bfloat16* kbase = kn + ((size_t)b * T_) * D_ + h * DH_;
  const __hip_bfloat16* vbase = vv + ((size_t)b * T_) * D_ + h * DH_;

#pragma unroll
  for (int ld = 0; ld < 4; ++ld) {
    int f = ld * 256 + tid;
    int rw = f >> 3, c8 = (f & 7) << 3;
    *(uint4*)(&Kb[rw * 72 + c8]) = *(const uint4*)(kbase + (size_t)pos[rw] * D_ + c8);
  }
#pragma unroll
  for (int ld = 0; ld < 2; ++ld) {
    int f = ld * 256 + tid;
    int rw = f >> 3, c8 = (f & 7) << 3;
    *(uint4*)(&PbQb[rw * 72 + c8]) = *(const uint4*)(qbase + (size_t)pos[rw] * D_ + c8);
  }
  // V: gather bf16 rows, 8x8 register transpose, b128 swizzled stores
  {
    const int w = tid >> 6, rl = tid & 7, d8 = (tid >> 3) & 7;
#pragma unroll
    for (int it = 0; it < 4; ++it) {
      int rw0 = it * 32 + w * 8;
      uint4 x = *(const uint4*)(vbase + (size_t)pos[rw0 + rl] * D_ + d8 * 8);
      unsigned short u[8];
      u[0] = x.x & 0xffff; u[1] = x.x >> 16;
      u[2] = x.y & 0xffff; u[3] = x.y >> 16;
      u[4] = x.z & 0xffff; u[5] = x.z >> 16;
      u[6] = x.w & 0xffff; u[7] = x.w >> 16;
#pragma unroll
      for (int k = 0; k < 3; ++k) {
        const int xm = 1 << k;
        const bool sel = (rl >> k) & 1;
#pragma unroll
        for (int j0 = 0; j0 < 8; ++j0) {
          if ((j0 >> k) & 1) continue;
          int j1 = j0 | (1 << k);
          unsigned int send = sel ? (unsigned int)u[j0] : (unsigned int)u[j1];
          unsigned int recv = (unsigned int)__shfl_xor((int)send, xm);
          if (sel) u[j0] = (unsigned short)recv; else u[j1] = (unsigned short)recv;
        }
      }
      int d = d8 * 8 + rl;
      uint4 y;
      y.x = (unsigned int)u[0] | ((unsigned int)u[1] << 16);
      y.y = (unsigned int)u[2] | ((unsigned int)u[3] << 16);
      y.z = (unsigned int)u[4] | ((unsigned int)u[5] << 16);
      y.w = (unsigned int)u[6] | ((unsigned int)u[7] << 16);
      *(uint4*)(&VbT[d * 136 + (rw0 ^ (((d >> 3) & 3) << 3))]) = y;
    }
  }
  __syncthreads();

  const int w = tid >> 6, lane = tid & 63;
  const int g = lane >> 4, l15 = lane & 15;
  const int q0 = w * 16;

  // --- dots
  bf16x8 af0 = *(const bf16x8*)(&PbQb[(q0 + l15) * 72 + g * 8]);
  bf16x8 af1 = *(const bf16x8*)(&PbQb[(q0 + l15) * 72 + 32 + g * 8]);
  f32x4 dacc[8];
#pragma unroll
  for (int n = 0; n < 8; ++n) dacc[n] = (f32x4){0.f, 0.f, 0.f, 0.f};
#pragma unroll
  for (int n = 0; n < 8; ++n) {
    bf16x8 b0 = *(const bf16x8*)(&Kb[(n * 16 + l15) * 72 + g * 8]);
    bf16x8 b1 = *(const bf16x8*)(&Kb[(n * 16 + l15) * 72 + 32 + g * 8]);
    dacc[n] = __builtin_amdgcn_mfma_f32_16x16x32_bf16(af0, b0, dacc[n], 0, 0, 0);
    dacc[n] = __builtin_amdgcn_mfma_f32_16x16x32_bf16(af1, b1, dacc[n], 0, 0, 0);
  }
  __syncthreads();   // Qb reads done before Pb overwrites

  // --- mask + softmax (no max subtraction; dots bounded ~|q|/8 <= ~1)
  int qpos[4], kpos[8];
#pragma unroll
  for (int reg = 0; reg < 4; ++reg) qpos[reg] = pos[q0 + g * 4 + reg];
#pragma unroll
  for (int n = 0; n < 8; ++n) kpos[n] = pos[n * 16 + l15];
  float pr[8][4];
#pragma unroll
  for (int reg = 0; reg < 4; ++reg) {
    float s = 0.f;
#pragma unroll
    for (int n = 0; n < 8; ++n) {
      float dv = dacc[n][reg];
      dv = (kpos[n] == qpos[reg]) ? -5.0e4f : dv;
      float e = __expf(dv);
      pr[n][reg] = e;
      s += e;
    }
    s += __shfl_xor(s, 1); s += __shfl_xor(s, 2);
    s += __shfl_xor(s, 4); s += __shfl_xor(s, 8);
    if (l15 == 0) {
      lsb[q0 + g * 4 + reg] = 1.0f / s;
      lgb[(((size_t)(bh * NH_ + r)) * T_ + ((c & 15) << 6)) + q0 + g * 4 + reg] = __logf(s);
    }
  }
#pragma unroll
  for (int n = 0; n < 8; ++n)
#pragma unroll
    for (int reg = 0; reg < 4; ++reg)
      PbQb[(q0 + g * 4 + reg) * 136 + n * 16 + l15] = __float2bfloat16(pr[n][reg]);
  const size_t slotbase = ((size_t)(bh * NH_ + r)) * T_ + ((c & 15) << 6);
  __syncthreads();

  // --- PV: O^T[d][q], normalized by lsb[q] at the write
  bf16x8 va[4];
#pragma unroll
  for (int s = 0; s < 4; ++s) {
    int dd = w * 16 + l15;
    va[s] = *(const bf16x8*)(&VbT[dd * 136 + ((s * 32 + g * 8) ^ (((dd >> 3) & 3) << 3))]);
  }
#pragma unroll
  for (int n = 0; n < 4; ++n) {
    f32x4 oa = (f32x4){0.f, 0.f, 0.f, 0.f};
#pragma unroll
    for (int s = 0; s < 4; ++s) {
      bf16x8 pb = *(const bf16x8*)(&PbQb[(n * 16 + l15) * 136 + s * 32 + g * 8]);
      oa = __builtin_amdgcn_mfma_f32_16x16x32_bf16(va[s], pb, oa, 0, 0, 0);
    }
    int q = n * 16 + l15;
    float inv = lsb[q];
    int d = w * 16 + g * 4;
    __hip_bfloat16 o4[4];
#pragma unroll
    for (int reg = 0; reg < 4; ++reg) o4[reg] = __float2bfloat16(oa[reg] * inv);
    *(uint2*)(&ob[(slotbase + q) * DH_ + d]) = *(uint2*)o4;
  }
}

// ---------------------------------------------------------------- round combine (gather via undo)
__global__ __launch_bounds__(256) void k_combine(const __hip_bfloat16* __restrict__ ob,
                                                 const float* __restrict__ lgb,
                                                 const int* __restrict__ undo,
                                                 __hip_bfloat16* __restrict__ attnb) {
  int g = threadIdx.x >> 6, lane = threadIdx.x & 63;
  int idx = blockIdx.x * 4 + g;
  int bh = idx >> 10, t = idx & (T_ - 1);
  int b = bh >> 3, h = bh & 7;
  int su[8];
  float lg[8];
  float m = -3.0e38f;
#pragma unroll
  for (int r = 0; r < 8; ++r) {
    su[r] = undo[((size_t)(bh * NH_ + r)) * T_ + t];
    lg[r] = lgb[((size_t)(bh * NH_ + r)) * T_ + su[r]];
    m = fmaxf(m, lg[r]);
  }
  float s = 0.f;
#pragma unroll
  for (int r = 0; r < 8; ++r) { lg[r] = __expf(lg[r] - m); s += lg[r]; }
  float invs = 1.0f / s;
  float o = 0.f;
#pragma unroll
  for (int r = 0; r < 8; ++r)
    o += lg[r] * invs * __bfloat162float(ob[(((size_t)(bh * NH_ + r)) * T_ + su[r]) * DH_ + lane]);
  attnb[((size_t)(b * T_ + t)) * D_ + h * DH_ + lane] = __float2bfloat16(o);
}

// ---------------------------------------------------------------- final reduction
__global__ void k_zero(float* __restrict__ p, int n) {
  int i = blockIdx.x * blockDim.x + threadIdx.x;
  if (i < n) p[i] = 0.f;
}

__global__ __launch_bounds__(256) void k_colsum(const float* __restrict__ xn,
                                                float* __restrict__ mean) {
  int b = blockIdx.x, dc = blockIdx.y, tc = blockIdx.z;
  int d = dc * 256 + threadIdx.x;
  float s = 0.f;
  for (int tt = 0; tt < 64; ++tt) {
    int t = tc * 64 + tt;
    s += xn[((size_t)(b * T_ + t)) * D_ + d];
  }
  atomicAdd(&mean[b * D_ + d], s);
}

__global__ __launch_bounds__(512) void k_fc(const float* __restrict__ mean,
                                            const float* __restrict__ Wfc,
                                            float* __restrict__ out) {
  int b = blockIdx.x, n = threadIdx.x;
  __shared__ float ms[512];
  ms[n] = mean[b * D_ + n] * (1.0f / 1024.0f);
  __syncthreads();
  float acc = 0.f;
  for (int d = 0; d < 512; ++d) acc += ms[d] * Wfc[(size_t)d * D_ + n];
  out[b * D_ + n] = acc;
}

// ---------------------------------------------------------------- launcher
extern "C" void kernel_launch(void* const* d_in, const int* in_sizes, int n_in,
                              void* d_out, int out_size, void* d_ws, size_t ws_size,
                              hipStream_t stream) {
  (void)in_sizes; (void)n_in; (void)out_size; (void)ws_size;
  const int*   ids  = (const int*)d_in[0];
  const float* te   = (const float*)d_in[1];
  const float* pe   = (const float*)d_in[2];
  const float* lag  = (const float*)d_in[3];
  const float* lab  = (const float*)d_in[4];
  const float* Wqk  = (const float*)d_in[5];
  const float* Wv   = (const float*)d_in[6];
  const float* Wo   = (const float*)d_in[7];
  const float* lfg  = (const float*)d_in[8];
  const float* lfb  = (const float*)d_in[9];
  const float* W1   = (const float*)d_in[10];
  const float* b1   = (const float*)d_in[11];
  const float* W2   = (const float*)d_in[12];
  const float* b2   = (const float*)d_in[13];
  const float* lnfg = (const float*)d_in[14];
  const float* lnfb = (const float*)d_in[15];
  const float* Wfc  = (const float*)d_in[16];
  const float* rot  = (const float*)d_in[17];

  char* ws = (char*)d_ws;
  size_t off = 0;
  auto carve = [&](size_t bytes) -> void* {
    void* p = ws + off;
    off += (bytes + 255) & ~(size_t)255;
    return p;
  };
  float* x1    = (float*)carve((size_t)ROWS_ * D_ * 4);
  float* x2    = (float*)carve((size_t)ROWS_ * D_ * 4);
  float* xn    = (float*)carve((size_t)ROWS_ * D_ * 4);
  float* qkb   = (float*)carve((size_t)ROWS_ * D_ * 4);
  __hip_bfloat16* vvb   = (__hip_bfloat16*)carve((size_t)ROWS_ * D_ * 2);
  __hip_bfloat16* qsb   = (__hip_bfloat16*)carve((size_t)ROWS_ * D_ * 2);
  __hip_bfloat16* knb   = (__hip_bfloat16*)carve((size_t)ROWS_ * D_ * 2);
  __hip_bfloat16* xnb   = (__hip_bfloat16*)carve((size_t)ROWS_ * D_ * 2);
  __hip_bfloat16* xnlo  = (__hip_bfloat16*)carve((size_t)ROWS_ * D_ * 2);
  __hip_bfloat16* attnb = (__hip_bfloat16*)carve((size_t)ROWS_ * D_ * 2);
  __hip_bfloat16* ob    = (__hip_bfloat16*)carve((size_t)BH_ * NH_ * T_ * DH_ * 2);  // 67 MB
  __hip_bfloat16* hid   = ob;  // alias: ob dead after combine; hid needs 32 MB
  unsigned char* bkt = (unsigned char*)carve((size_t)BH_ * NH_ * T_);
  int*   stb   = (int*)carve((size_t)BH_ * NH_ * T_ * 4);
  int*   undo  = (int*)carve((size_t)BH_ * NH_ * T_ * 4);
  float* lgb   = (float*)carve((size_t)BH_ * NH_ * T_ * 4);
  float* meanb = (float*)carve((size_t)B_ * D_ * 4);
  __hip_bfloat16* WvT  = (__hip_bfloat16*)carve((size_t)DEPTH_ * D_ * D_ * 2);
  __hip_bfloat16* WoT  = (__hip_bfloat16*)carve((size_t)DEPTH_ * D_ * D_ * 2);
  __hip_bfloat16* W1T  = (__hip_bfloat16*)carve((size_t)DEPTH_ * D_ * FF_ * 2);
  __hip_bfloat16* W2T  = (__hip_bfloat16*)carve((size_t)DEPTH_ * FF_ * D_ * 2);
  __hip_bfloat16* WqhT = (__hip_bfloat16*)carve((size_t)DEPTH_ * D_ * D_ * 2);
  __hip_bfloat16* WqlT = (__hip_bfloat16*)carve((size_t)DEPTH_ * D_ * D_ * 2);

  k_wt<<<dim3(D_ / 32, D_ / 32, DEPTH_), 256, 0, stream>>>(Wv, WvT, D_, D_);
  k_wt<<<dim3(D_ / 32, D_ / 32, DEPTH_), 256, 0, stream>>>(Wo, WoT, D_, D_);
  k_wt<<<dim3(FF_ / 32, D_ / 32, DEPTH_), 256, 0, stream>>>(W1, W1T, D_, FF_);
  k_wt<<<dim3(D_ / 32, FF_ / 32, DEPTH_), 256, 0, stream>>>(W2, W2T, FF_, D_);
  k_wt2<<<dim3(D_ / 32, D_ / 32, DEPTH_), 256, 0, stream>>>(Wqk, WqhT, WqlT, D_, D_);

  k_embed<<<ROWS_, 128, 0, stream>>>(ids, te, pe, x1, x2);

  for (int l = 0; l < DEPTH_; ++l) {
    const __hip_bfloat16* wvt = WvT + (size_t)l * D_ * D_;
    const __hip_bfloat16* wot = WoT + (size_t)l * D_ * D_;
    const __hip_bfloat16* w1t = W1T + (size_t)l * D_ * FF_;
    const __hip_bfloat16* w2t = W2T + (size_t)l * FF_ * D_;
    const __hip_bfloat16* wqh = WqhT + (size_t)l * D_ * D_;
    const __hip_bfloat16* wql = WqlT + (size_t)l * D_ * D_;

    k_ln<<<ROWS_ / 4, 256, 0, stream>>>(x2, nullptr, lag + l * D_, lab + l * D_, nullptr, xnb, xnlo);
    k_qgemm<<<dim3(D_ / 128, ROWS_ / 128), 256, 0, stream>>>(xnb, xnlo, wqh, wql, qkb, D_, D_);
    k_bgemm<4><<<dim3(D_ / 128, ROWS_ / 128), 256, 0, stream>>>(xnb, wvt, nullptr, vvb, D_, D_);
    k_prep<<<ROWS_ / 4, 256, 0, stream>>>(qkb, qsb, knb);
    k_bucket<<<512, 128, 0, stream>>>(qkb, rot + (size_t)l * 4096, bkt);
    k_sort<<<512, 1024, 0, stream>>>(bkt, stb, undo);
    k_attn<<<dim3(NC_, BH_), 256, 0, stream>>>(qsb, knb, vvb, stb, ob, lgb);
    k_combine<<<BH_ * T_ / 4, 256, 0, stream>>>(ob, lgb, undo, attnb);
    k_bgemm<1><<<dim3(D_ / 128, ROWS_ / 128), 256, 0, stream>>>(attnb, wot, nullptr, x1, D_, D_);

    k_ln<<<ROWS_ / 4, 256, 0, stream>>>(x1, nullptr, lfg + l * D_, lfb + l * D_, nullptr, xnb, nullptr);
    k_bgemm<2><<<dim3(FF_ / 128, ROWS_ / 128), 256, 0, stream>>>(xnb, w1t, b1 + l * FF_, hid, FF_, D_);
    k_bgemm<3><<<dim3(D_ / 128, ROWS_ / 128), 256, 0, stream>>>(hid, w2t, b2 + l * D_, x2, D_, FF_);
  }

  k_ln<<<ROWS_ / 4, 256, 0, stream>>>(x1, x2, lnfg, lnfb, xn, nullptr, nullptr);
  k_zero<<<16, 256, 0, stream>>>(meanb, B_ * D_);
  k_colsum<<<dim3(B_, 2, 16), 256, 0, stream>>>(xn, meanb);
  k_fc<<<B_, 512, 0, stream>>>(meanb, Wfc, (float*)d_out);
}

// Round 11
// 2872.935 us; speedup vs baseline: 3.3649x; 1.1135x over previous
//
#include <hip/hip_runtime.h>
#include <hip/hip_bf16.h>
#include <cstdint>
#include <cstddef>

#define B_ 8
#define T_ 1024
#define D_ 512
#define H_ 8
#define DH_ 64
#define DEPTH_ 8
#define FF_ 2048
#define NH_ 8
#define BS_ 64
#define NB_ 16
#define NC_ 128
#define BH_ 64
#define ROWS_ 8192   // B*T

typedef __attribute__((ext_vector_type(8))) short bf16x8;
typedef __attribute__((ext_vector_type(4))) float f32x4;

typedef __attribute__((address_space(1))) const unsigned int g_u32;
typedef __attribute__((address_space(3))) unsigned int l_u32;
__device__ __forceinline__ void gload16(const void* g, void* l) {
  __builtin_amdgcn_global_load_lds((g_u32*)g, (l_u32*)l, 16, 0, 0);
}

// ---------------------------------------------------------------- utilities
__device__ __forceinline__ float wave_sum(float v) {
#pragma unroll
  for (int o = 1; o < 64; o <<= 1) v += __shfl_xor(v, o);
  return v;
}

__device__ __forceinline__ float gelu_f(float u) {
  float c = u + 0.044715f * u * u * u;
  float t = tanhf(0.7978845608028654f * c);
  return 0.5f * u * (1.0f + t);
}

// ---------------------------------------------------------------- embedding
__global__ __launch_bounds__(128) void k_embed(const int* __restrict__ ids,
                                               const float* __restrict__ te,
                                               const float* __restrict__ pe,
                                               float* __restrict__ x1,
                                               float* __restrict__ x2) {
  int bt = blockIdx.x;
  int t = bt & (T_ - 1);
  int d = threadIdx.x * 4;
  int id = ids[bt];
  float4 v = *(const float4*)(te + (size_t)id * D_ + d);
  float4 p = *(const float4*)(pe + (size_t)t * D_ + d);
  v.x += p.x; v.y += p.y; v.z += p.z; v.w += p.w;
  *(float4*)(x1 + (size_t)bt * D_ + d) = v;
  *(float4*)(x2 + (size_t)bt * D_ + d) = v;
}

// ---------------------------------------------------------------- weight transpose + bf16
__global__ __launch_bounds__(256) void k_wt(const float* __restrict__ W,
                                            __hip_bfloat16* __restrict__ WT,
                                            int K, int N) {
  const float* Wl = W + (size_t)blockIdx.z * K * N;
  __hip_bfloat16* WTl = WT + (size_t)blockIdx.z * K * N;
  __shared__ float tile[32][33];
  int n0 = blockIdx.x * 32, k0 = blockIdx.y * 32;
  int tx = threadIdx.x & 31, ty = threadIdx.x >> 5;  // 32 x 8
#pragma unroll
  for (int i = 0; i < 32; i += 8)
    tile[ty + i][tx] = Wl[(size_t)(k0 + ty + i) * N + n0 + tx];
  __syncthreads();
#pragma unroll
  for (int i = 0; i < 32; i += 8)
    WTl[(size_t)(n0 + ty + i) * K + k0 + tx] = __float2bfloat16(tile[tx][ty + i]);
}

// ---------------------------------------------------------------- weight transpose + hi/lo bf16 split
__global__ __launch_bounds__(256) void k_wt2(const float* __restrict__ W,
                                             __hip_bfloat16* __restrict__ WhT,
                                             __hip_bfloat16* __restrict__ WlT,
                                             int K, int N) {
  const float* Wl = W + (size_t)blockIdx.z * K * N;
  __hip_bfloat16* WhTl = WhT + (size_t)blockIdx.z * K * N;
  __hip_bfloat16* WlTl = WlT + (size_t)blockIdx.z * K * N;
  __shared__ float tile[32][33];
  int n0 = blockIdx.x * 32, k0 = blockIdx.y * 32;
  int tx = threadIdx.x & 31, ty = threadIdx.x >> 5;
#pragma unroll
  for (int i = 0; i < 32; i += 8)
    tile[ty + i][tx] = Wl[(size_t)(k0 + ty + i) * N + n0 + tx];
  __syncthreads();
#pragma unroll
  for (int i = 0; i < 32; i += 8) {
    float v = tile[tx][ty + i];
    __hip_bfloat16 hi = __float2bfloat16(v);
    float lo = v - __bfloat162float(hi);
    size_t idx = (size_t)(n0 + ty + i) * K + k0 + tx;
    WhTl[idx] = hi;
    WlTl[idx] = __float2bfloat16(lo);
  }
}

// ---------------------------------------------------------------- layernorm
// yb = bf16(out), ylo = bf16(out - yb) (split residual); all outputs nullable
__global__ __launch_bounds__(256) void k_ln(const float* __restrict__ x,
                                            const float* __restrict__ xb,
                                            const float* __restrict__ g,
                                            const float* __restrict__ bb,
                                            float* __restrict__ y,
                                            __hip_bfloat16* __restrict__ yb,
                                            __hip_bfloat16* __restrict__ ylo) {
  int w = threadIdx.x >> 6, lane = threadIdx.x & 63;
  size_t row = (size_t)blockIdx.x * 4 + w;
  const float* xr = x + row * D_ + lane * 8;
  float v[8];
  *(float4*)(v)     = *(const float4*)(xr);
  *(float4*)(v + 4) = *(const float4*)(xr + 4);
  if (xb) {
    const float* x2r = xb + row * D_ + lane * 8;
    float u[8];
    *(float4*)(u)     = *(const float4*)(x2r);
    *(float4*)(u + 4) = *(const float4*)(x2r + 4);
#pragma unroll
    for (int i = 0; i < 8; ++i) v[i] = 0.5f * (v[i] + u[i]);
  }
  float s = 0.f;
#pragma unroll
  for (int i = 0; i < 8; ++i) s += v[i];
  s = wave_sum(s);
  float m = s * (1.0f / D_);
  float q = 0.f;
#pragma unroll
  for (int i = 0; i < 8; ++i) { float d = v[i] - m; q += d * d; }
  q = wave_sum(q);
  float inv = 1.0f / sqrtf(q * (1.0f / D_) + 1e-5f);
  float gg[8], bv[8];
  *(float4*)(gg)     = *(const float4*)(g + lane * 8);
  *(float4*)(gg + 4) = *(const float4*)(g + lane * 8 + 4);
  *(float4*)(bv)     = *(const float4*)(bb + lane * 8);
  *(float4*)(bv + 4) = *(const float4*)(bb + lane * 8 + 4);
  float o[8];
#pragma unroll
  for (int i = 0; i < 8; ++i) o[i] = (v[i] - m) * inv * gg[i] + bv[i];
  if (y) {
    float* yr = y + row * D_ + lane * 8;
    *(float4*)(yr)     = *(float4*)(o);
    *(float4*)(yr + 4) = *(float4*)(o + 4);
  }
  if (yb) {
    __hip_bfloat16 o16[8];
#pragma unroll
    for (int i = 0; i < 8; ++i) o16[i] = __float2bfloat16(o[i]);
    *(uint4*)(yb + row * D_ + lane * 8) = *(uint4*)o16;
    if (ylo) {
      __hip_bfloat16 l16[8];
#pragma unroll
      for (int i = 0; i < 8; ++i)
        l16[i] = __float2bfloat16(o[i] - __bfloat162float(o16[i]));
      *(uint4*)(ylo + row * D_ + lane * 8) = *(uint4*)l16;
    }
  }
}

// ---------------------------------------------------------------- split-bf16 MFMA GEMM (qk projection)
// C(f32) = (Ah+Al) x (Bh+Bl)^T  ~=  Ah.Bh + Ah.Bl + Al.Bh   (error ~2^-18 rel)
__global__ __launch_bounds__(256) void k_qgemm(const __hip_bfloat16* __restrict__ Ah,
                                               const __hip_bfloat16* __restrict__ Al,
                                               const __hip_bfloat16* __restrict__ BhT,
                                               const __hip_bfloat16* __restrict__ BlT,
                                               float* __restrict__ C, int N, int K) {
  __shared__ __align__(16) __hip_bfloat16 Ash[128 * 32];
  __shared__ __align__(16) __hip_bfloat16 Asl[128 * 32];
  __shared__ __align__(16) __hip_bfloat16 Bsh[128 * 32];
  __shared__ __align__(16) __hip_bfloat16 Bsl[128 * 32];
  const int bn0 = blockIdx.x * 128;
  const int bm0 = blockIdx.y * 128;
  const int tid = threadIdx.x;
  const int w = tid >> 6, lane = tid & 63;
  const int wy = w >> 1, wx = w & 1;
  const int g = lane >> 4, lr = lane & 15;
  f32x4 acc[4][4] = {};
  const size_t aoff = (size_t)bm0 * K;
  const size_t boff = (size_t)bn0 * K;

  for (int k0 = 0; k0 < K; k0 += 32) {
#pragma unroll
    for (int it = 0; it < 2; ++it) {
      int f = it * 256 + w * 64 + lane;
      int row = f >> 2;
      int kc = ((f & 3) ^ ((row >> 1) & 3)) << 3;
      size_t ga = aoff + (size_t)row * K + k0 + kc;
      size_t gb = boff + (size_t)row * K + k0 + kc;
      int lo = (it * 256 + w * 64) * 8;
      gload16(Ah + ga, &Ash[lo]);
      gload16(Al + ga, &Asl[lo]);
      gload16(BhT + gb, &Bsh[lo]);
      gload16(BlT + gb, &Bsl[lo]);
    }
    __syncthreads();
    bf16x8 ah[4], al[4], bh[4], bl[4];
#pragma unroll
    for (int m = 0; m < 4; ++m) {
      int row = wy * 64 + m * 16 + lr;
      int o = row * 32 + ((g ^ ((row >> 1) & 3)) << 3);
      ah[m] = *(const bf16x8*)(&Ash[o]);
      al[m] = *(const bf16x8*)(&Asl[o]);
    }
#pragma unroll
    for (int n = 0; n < 4; ++n) {
      int row = wx * 64 + n * 16 + lr;
      int o = row * 32 + ((g ^ ((row >> 1) & 3)) << 3);
      bh[n] = *(const bf16x8*)(&Bsh[o]);
      bl[n] = *(const bf16x8*)(&Bsl[o]);
    }
#pragma unroll
    for (int m = 0; m < 4; ++m)
#pragma unroll
      for (int n = 0; n < 4; ++n) {
        acc[m][n] = __builtin_amdgcn_mfma_f32_16x16x32_bf16(ah[m], bh[n], acc[m][n], 0, 0, 0);
        acc[m][n] = __builtin_amdgcn_mfma_f32_16x16x32_bf16(ah[m], bl[n], acc[m][n], 0, 0, 0);
        acc[m][n] = __builtin_amdgcn_mfma_f32_16x16x32_bf16(al[m], bh[n], acc[m][n], 0, 0, 0);
      }
    __syncthreads();
  }

  const int colb = bn0 + wx * 64 + lr;
  const int rowb = bm0 + wy * 64 + (g << 2);
#pragma unroll
  for (int m = 0; m < 4; ++m)
#pragma unroll
    for (int n = 0; n < 4; ++n) {
      int c = colb + n * 16;
      int r0 = rowb + m * 16;
#pragma unroll
      for (int j = 0; j < 4; ++j)
        C[(size_t)(r0 + j) * N + c] = acc[m][n][j];
    }
}

// ---------------------------------------------------------------- qk prep: Q*0.125 and K/|K| (per head), bf16
__global__ __launch_bounds__(256) void k_prep(const float* __restrict__ qkb,
                                              __hip_bfloat16* __restrict__ qsb,
                                              __hip_bfloat16* __restrict__ knb) {
  int w = threadIdx.x >> 6, lane = threadIdx.x & 63;
  size_t row = (size_t)blockIdx.x * 4 + w;
  const float* xr = qkb + row * D_ + lane * 8;
  float v[8];
  *(float4*)(v)     = *(const float4*)(xr);
  *(float4*)(v + 4) = *(const float4*)(xr + 4);
  float ss = 0.f;
#pragma unroll
  for (int i = 0; i < 8; ++i) ss += v[i] * v[i];
  ss += __shfl_xor(ss, 1); ss += __shfl_xor(ss, 2); ss += __shfl_xor(ss, 4);
  float inv = 1.0f / (sqrtf(ss) + 1e-8f);
  __hip_bfloat16 qo[8], ko[8];
#pragma unroll
  for (int i = 0; i < 8; ++i) {
    qo[i] = __float2bfloat16(v[i] * 0.125f);
    ko[i] = __float2bfloat16(v[i] * inv);
  }
  *(uint4*)(qsb + row * D_ + lane * 8) = *(uint4*)qo;
  *(uint4*)(knb + row * D_ + lane * 8) = *(uint4*)ko;
}

// ---------------------------------------------------------------- bf16 MFMA GEMM
// EPI: 0 C(f32)=AB ; 1 C(f32)+=AB ; 2 C(bf16)=gelu(AB+bias) ; 3 C(f32)+=AB+bias ; 4 C(bf16)=AB
template <int EPI>
__global__ __launch_bounds__(256) void k_bgemm(const __hip_bfloat16* __restrict__ A,
                                               const __hip_bfloat16* __restrict__ BT,
                                               const float* __restrict__ bias,
                                               void* __restrict__ Cv,
                                               int N, int K) {
  __shared__ __align__(16) __hip_bfloat16 As[128 * 32];
  __shared__ __align__(16) __hip_bfloat16 Bs[128 * 32];
  const int bn0 = blockIdx.x * 128;
  const int bm0 = blockIdx.y * 128;
  const int tid = threadIdx.x;
  const int w = tid >> 6, lane = tid & 63;
  const int wy = w >> 1, wx = w & 1;
  const int g = lane >> 4, lr = lane & 15;
  f32x4 acc[4][4] = {};

  const __hip_bfloat16* Abase = A + (size_t)bm0 * K;
  const __hip_bfloat16* Bbase = BT + (size_t)bn0 * K;

  for (int k0 = 0; k0 < K; k0 += 32) {
#pragma unroll
    for (int it = 0; it < 2; ++it) {
      int f = it * 256 + w * 64 + lane;
      int row = f >> 2;
      int kc = ((f & 3) ^ ((row >> 1) & 3)) << 3;
      gload16(Abase + (size_t)row * K + k0 + kc, &As[(it * 256 + w * 64) * 8]);
      gload16(Bbase + (size_t)row * K + k0 + kc, &Bs[(it * 256 + w * 64) * 8]);
    }
    __syncthreads();
    bf16x8 af[4], bfr[4];
#pragma unroll
    for (int m = 0; m < 4; ++m) {
      int row = wy * 64 + m * 16 + lr;
      af[m] = *(const bf16x8*)(&As[row * 32 + ((g ^ ((row >> 1) & 3)) << 3)]);
    }
#pragma unroll
    for (int n = 0; n < 4; ++n) {
      int row = wx * 64 + n * 16 + lr;
      bfr[n] = *(const bf16x8*)(&Bs[row * 32 + ((g ^ ((row >> 1) & 3)) << 3)]);
    }
#pragma unroll
    for (int m = 0; m < 4; ++m)
#pragma unroll
      for (int n = 0; n < 4; ++n)
        acc[m][n] = __builtin_amdgcn_mfma_f32_16x16x32_bf16(af[m], bfr[n], acc[m][n], 0, 0, 0);
    __syncthreads();
  }

  const int colb = bn0 + wx * 64 + lr;
  const int rowb = bm0 + wy * 64 + (g << 2);
#pragma unroll
  for (int m = 0; m < 4; ++m) {
#pragma unroll
    for (int n = 0; n < 4; ++n) {
      int c = colb + n * 16;
      int r0 = rowb + m * 16;
      float bsv = (EPI == 2 || EPI == 3) ? bias[c] : 0.f;
#pragma unroll
      for (int j = 0; j < 4; ++j) {
        float vlu = acc[m][n][j] + bsv;
        size_t idx = (size_t)(r0 + j) * N + c;
        if (EPI == 0) ((float*)Cv)[idx] = vlu;
        else if (EPI == 1) ((float*)Cv)[idx] += vlu;
        else if (EPI == 2) ((__hip_bfloat16*)Cv)[idx] = __float2bfloat16(gelu_f(vlu));
        else if (EPI == 3) ((float*)Cv)[idx] += vlu;
        else ((__hip_bfloat16*)Cv)[idx] = __float2bfloat16(vlu);
      }
    }
  }
}

// ---------------------------------------------------------------- LSH bucket ids
__global__ __launch_bounds__(128) void k_bucket(const float* __restrict__ qk,
                                                const float* __restrict__ rotL,
                                                unsigned char* __restrict__ bkt) {
  int blk = blockIdx.x;
  int tc = blk & 7, h = (blk >> 3) & 7, b = blk >> 6;
  int t0 = tc << 7;
  __shared__ float qs[128][65];
  __shared__ float rs[4096];
  int tid = threadIdx.x;
  for (int f = tid; f < 4096; f += 128) rs[f] = rotL[f];
  const float* base = qk + ((size_t)(b * T_ + t0)) * D_ + h * DH_;
  for (int f = tid; f < 2048; f += 128) {
    int rw = f >> 4, c4 = (f & 15) << 2;
    float4 v = *(const float4*)(base + (size_t)rw * D_ + c4);
    qs[rw][c4] = v.x; qs[rw][c4 + 1] = v.y; qs[rw][c4 + 2] = v.z; qs[rw][c4 + 3] = v.w;
  }
  __syncthreads();
  float s[64];
#pragma unroll
  for (int jr = 0; jr < 64; ++jr) s[jr] = 0.f;
  for (int d = 0; d < 64; ++d) {
    float q = qs[tid][d];
    const float* rp = rs + d * 64;
#pragma unroll
    for (int j4 = 0; j4 < 16; ++j4) {
      float4 rv = *(const float4*)(rp + j4 * 4);
      s[j4 * 4 + 0] += q * rv.x; s[j4 * 4 + 1] += q * rv.y;
      s[j4 * 4 + 2] += q * rv.z; s[j4 * 4 + 3] += q * rv.w;
    }
  }
  int bh = b * H_ + h;
#pragma unroll
  for (int r = 0; r < 8; ++r) {
    float best = s[r * 8];
    int bi = 0;
#pragma unroll
    for (int idx = 1; idx < 16; ++idx) {
      float v = (idx < 8) ? s[r * 8 + idx] : -s[r * 8 + idx - 8];
      if (v > best) { best = v; bi = idx; }
    }
    bkt[((size_t)(bh * NH_ + r)) * T_ + t0 + tid] = (unsigned char)bi;
  }
}

// ---------------------------------------------------------------- stable counting sort + undo
__global__ __launch_bounds__(1024) void k_sort(const unsigned char* __restrict__ bkt,
                                               int* __restrict__ st,
                                               int* __restrict__ undo) {
  int r = blockIdx.x & 7, bh = blockIdx.x >> 3;
  int t = threadIdx.x;
  int bk = bkt[((size_t)(bh * NH_ + r)) * T_ + t];
  int w = t >> 6, lane = t & 63;
  __shared__ int cnt[16][16];
  __shared__ int off[16][16];
  __shared__ int tot[16];
  __shared__ int stt[16];
  unsigned long long below = (1ULL << lane) - 1ULL;
  int myrank = 0;
#pragma unroll
  for (int bb = 0; bb < 16; ++bb) {
    unsigned long long m = __ballot(bk == bb);
    if (bk == bb) myrank = __popcll(m & below);
    if (lane == 0) cnt[w][bb] = __popcll(m);
  }
  __syncthreads();
  if (t < 16) {
    int run = 0;
    for (int ww = 0; ww < 16; ++ww) { off[ww][t] = run; run += cnt[ww][t]; }
    tot[t] = run;
  }
  __syncthreads();
  if (t == 0) {
    int run = 0;
    for (int bb = 0; bb < 16; ++bb) { stt[bb] = run; run += tot[bb]; }
  }
  __syncthreads();
  int pos = stt[bk] + off[w][bk] + myrank;
  st[((size_t)(bh * NH_ + r)) * T_ + pos] = t;
  undo[((size_t)(bh * NH_ + r)) * T_ + t] = pos;
}

// ---------------------------------------------------------------- chunked attention (MFMA, bf16 staged)
// grid (c=128, bh=64); block 256 (4 waves). No max pass (dots bounded, masked -5e4 underflows
// to 0); P normalized in-register before store. LDS kept at 53760 B (3 blocks/CU boundary).
__global__ __launch_bounds__(256) void k_attn(const __hip_bfloat16* __restrict__ qs,
                                              const __hip_bfloat16* __restrict__ kn,
                                              const __hip_bfloat16* __restrict__ vv,
                                              const int* __restrict__ st,
                                              __hip_bfloat16* __restrict__ ob,
                                              float* __restrict__ lgb) {
  __shared__ __align__(16) __hip_bfloat16 Kb[128 * 72];
  __shared__ __align__(16) __hip_bfloat16 VbT[64 * 136];   // [d][key], key-octet XOR-swizzled by (d>>3)&3
  __shared__ __align__(16) __hip_bfloat16 PbQb[64 * 136];  // Qb stride 72, then Pb stride 136
  __shared__ int pos[128];

  const int c = blockIdx.x, bh = blockIdx.y;
  const int b = bh >> 3, h = bh & 7;
  const int r = c >> 4;
  const int pc = (c + NC_ - 1) & (NC_ - 1);
  const int tid = threadIdx.x;

  if (tid < 128) {
    int sc = (tid < 64) ? c : pc;
    int slot = ((sc & 15) << 6) + (tid & 63);
    pos[tid] = st[((size_t)(bh * NH_ + (sc >> 4))) * T_ + slot];
  }
  __syncthreads();

  const __hip_bfloat16* qbase = qs + ((size_t)b * T_) * D_ + h * DH_;
  const __hip_bfloat16* kbase = kn + ((size_t)b * T_) * D_ + h * DH_;
  const __hip_bfloat16* vbase = vv + ((size_t)b * T_) * D_ + h * DH_;

#pragma unroll
  for (int ld = 0; ld < 4; ++ld) {
    int f = ld * 256 + tid;
    int rw = f >> 3, c8 = (f & 7) << 3;
    *(uint4*)(&Kb[rw * 72 + c8]) = *(const uint4*)(kbase + (size_t)pos[rw] * D_ + c8);
  }
#pragma unroll
  for (int ld = 0; ld < 2; ++ld) {
    int f = ld * 256 + tid;
    int rw = f >> 3, c8 = (f & 7) << 3;
    *(uint4*)(&PbQb[rw * 72 + c8]) = *(const uint4*)(qbase + (size_t)pos[rw] * D_ + c8);
  }
  // V: gather bf16 rows, 8x8 register transpose, b128 swizzled stores
  {
    const int w = tid >> 6, rl = tid & 7, d8 = (tid >> 3) & 7;
#pragma unroll
    for (int it = 0; it < 4; ++it) {
      int rw0 = it * 32 + w * 8;
      uint4 x = *(const uint4*)(vbase + (size_t)pos[rw0 + rl] * D_ + d8 * 8);
      unsigned short u[8];
      u[0] = x.x & 0xffff; u[1] = x.x >> 16;
      u[2] = x.y & 0xffff; u[3] = x.y >> 16;
      u[4] = x.z & 0xffff; u[5] = x.z >> 16;
      u[6] = x.w & 0xffff; u[7] = x.w >> 16;
#pragma unroll
      for (int k = 0; k < 3; ++k) {
        const int xm = 1 << k;
        const bool sel = (rl >> k) & 1;
#pragma unroll
        for (int j0 = 0; j0 < 8; ++j0) {
          if ((j0 >> k) & 1) continue;
          int j1 = j0 | (1 << k);
          unsigned int send = sel ? (unsigned int)u[j0] : (unsigned int)u[j1];
          unsigned int recv = (unsigned int)__shfl_xor((int)send, xm);
          if (sel) u[j0] = (unsigned short)recv; else u[j1] = (unsigned short)recv;
        }
      }
      int d = d8 * 8 + rl;
      uint4 y;
      y.x = (unsigned int)u[0] | ((unsigned int)u[1] << 16);
      y.y = (unsigned int)u[2] | ((unsigned int)u[3] << 16);
      y.z = (unsigned int)u[4] | ((unsigned int)u[5] << 16);
      y.w = (unsigned int)u[6] | ((unsigned int)u[7] << 16);
      *(uint4*)(&VbT[d * 136 + (rw0 ^ (((d >> 3) & 3) << 3))]) = y;
    }
  }
  __syncthreads();

  const int w = tid >> 6, lane = tid & 63;
  const int g = lane >> 4, l15 = lane & 15;
  const int q0 = w * 16;

  // --- dots
  bf16x8 af0 = *(const bf16x8*)(&PbQb[(q0 + l15) * 72 + g * 8]);
  bf16x8 af1 = *(const bf16x8*)(&PbQb[(q0 + l15) * 72 + 32 + g * 8]);
  f32x4 dacc[8];
#pragma unroll
  for (int n = 0; n < 8; ++n) dacc[n] = (f32x4){0.f, 0.f, 0.f, 0.f};
#pragma unroll
  for (int n = 0; n < 8; ++n) {
    bf16x8 b0 = *(const bf16x8*)(&Kb[(n * 16 + l15) * 72 + g * 8]);
    bf16x8 b1 = *(const bf16x8*)(&Kb[(n * 16 + l15) * 72 + 32 + g * 8]);
    dacc[n] = __builtin_amdgcn_mfma_f32_16x16x32_bf16(af0, b0, dacc[n], 0, 0, 0);
    dacc[n] = __builtin_amdgcn_mfma_f32_16x16x32_bf16(af1, b1, dacc[n], 0, 0, 0);
  }
  __syncthreads();   // Qb reads done before Pb overwrites

  // --- mask + softmax (no max subtraction; dots bounded ~|q|/8 <= ~1); normalize in-register
  int qpos[4], kpos[8];
#pragma unroll
  for (int reg = 0; reg < 4; ++reg) qpos[reg] = pos[q0 + g * 4 + reg];
#pragma unroll
  for (int n = 0; n < 8; ++n) kpos[n] = pos[n * 16 + l15];
  float pr[8][4];
#pragma unroll
  for (int reg = 0; reg < 4; ++reg) {
    float s = 0.f;
#pragma unroll
    for (int n = 0; n < 8; ++n) {
      float dv = dacc[n][reg];
      dv = (kpos[n] == qpos[reg]) ? -5.0e4f : dv;
      float e = __expf(dv);
      pr[n][reg] = e;
      s += e;
    }
    s += __shfl_xor(s, 1); s += __shfl_xor(s, 2);
    s += __shfl_xor(s, 4); s += __shfl_xor(s, 8);
    float isc = 1.0f / s;
#pragma unroll
    for (int n = 0; n < 8; ++n) pr[n][reg] *= isc;
    if (l15 == 0)
      lgb[(((size_t)(bh * NH_ + r)) * T_ + ((c & 15) << 6)) + q0 + g * 4 + reg] = __logf(s);
  }
#pragma unroll
  for (int n = 0; n < 8; ++n)
#pragma unroll
    for (int reg = 0; reg < 4; ++reg)
      PbQb[(q0 + g * 4 + reg) * 136 + n * 16 + l15] = __float2bfloat16(pr[n][reg]);
  const size_t slotbase = ((size_t)(bh * NH_ + r)) * T_ + ((c & 15) << 6);
  __syncthreads();

  // --- PV: O^T[d][q]
  bf16x8 va[4];
#pragma unroll
  for (int s = 0; s < 4; ++s) {
    int dd = w * 16 + l15;
    va[s] = *(const bf16x8*)(&VbT[dd * 136 + ((s * 32 + g * 8) ^ (((dd >> 3) & 3) << 3))]);
  }
#pragma unroll
  for (int n = 0; n < 4; ++n) {
    f32x4 oa = (f32x4){0.f, 0.f, 0.f, 0.f};
#pragma unroll
    for (int s = 0; s < 4; ++s) {
      bf16x8 pb = *(const bf16x8*)(&PbQb[(n * 16 + l15) * 136 + s * 32 + g * 8]);
      oa = __builtin_amdgcn_mfma_f32_16x16x32_bf16(va[s], pb, oa, 0, 0, 0);
    }
    int q = n * 16 + l15;
    int d = w * 16 + g * 4;
    __hip_bfloat16 o4[4];
#pragma unroll
    for (int reg = 0; reg < 4; ++reg) o4[reg] = __float2bfloat16(oa[reg]);
    *(uint2*)(&ob[(slotbase + q) * DH_ + d]) = *(uint2*)o4;
  }
}

// ---------------------------------------------------------------- round combine (gather via undo)
__global__ __launch_bounds__(256) void k_combine(const __hip_bfloat16* __restrict__ ob,
                                                 const float* __restrict__ lgb,
                                                 const int* __restrict__ undo,
                                                 __hip_bfloat16* __restrict__ attnb) {
  int g = threadIdx.x >> 6, lane = threadIdx.x & 63;
  int idx = blockIdx.x * 4 + g;
  int bh = idx >> 10, t = idx & (T_ - 1);
  int b = bh >> 3, h = bh & 7;
  int su[8];
  float lg[8];
  float m = -3.0e38f;
#pragma unroll
  for (int r = 0; r < 8; ++r) {
    su[r] = undo[((size_t)(bh * NH_ + r)) * T_ + t];
    lg[r] = lgb[((size_t)(bh * NH_ + r)) * T_ + su[r]];
    m = fmaxf(m, lg[r]);
  }
  float s = 0.f;
#pragma unroll
  for (int r = 0; r < 8; ++r) { lg[r] = __expf(lg[r] - m); s += lg[r]; }
  float invs = 1.0f / s;
  float o = 0.f;
#pragma unroll
  for (int r = 0; r < 8; ++r)
    o += lg[r] * invs * __bfloat162float(ob[(((size_t)(bh * NH_ + r)) * T_ + su[r]) * DH_ + lane]);
  attnb[((size_t)(b * T_ + t)) * D_ + h * DH_ + lane] = __float2bfloat16(o);
}

// ---------------------------------------------------------------- final reduction
__global__ void k_zero(float* __restrict__ p, int n) {
  int i = blockIdx.x * blockDim.x + threadIdx.x;
  if (i < n) p[i] = 0.f;
}

__global__ __launch_bounds__(256) void k_colsum(const float* __restrict__ xn,
                                                float* __restrict__ mean) {
  int b = blockIdx.x, dc = blockIdx.y, tc = blockIdx.z;
  int d = dc * 256 + threadIdx.x;
  float s = 0.f;
  for (int tt = 0; tt < 64; ++tt) {
    int t = tc * 64 + tt;
    s += xn[((size_t)(b * T_ + t)) * D_ + d];
  }
  atomicAdd(&mean[b * D_ + d], s);
}

__global__ __launch_bounds__(512) void k_fc(const float* __restrict__ mean,
                                            const float* __restrict__ Wfc,
                                            float* __restrict__ out) {
  int b = blockIdx.x, n = threadIdx.x;
  __shared__ float ms[512];
  ms[n] = mean[b * D_ + n] * (1.0f / 1024.0f);
  __syncthreads();
  float acc = 0.f;
  for (int d = 0; d < 512; ++d) acc += ms[d] * Wfc[(size_t)d * D_ + n];
  out[b * D_ + n] = acc;
}

// ---------------------------------------------------------------- launcher
extern "C" void kernel_launch(void* const* d_in, const int* in_sizes, int n_in,
                              void* d_out, int out_size, void* d_ws, size_t ws_size,
                              hipStream_t stream) {
  (void)in_sizes; (void)n_in; (void)out_size; (void)ws_size;
  const int*   ids  = (const int*)d_in[0];
  const float* te   = (const float*)d_in[1];
  const float* pe   = (const float*)d_in[2];
  const float* lag  = (const float*)d_in[3];
  const float* lab  = (const float*)d_in[4];
  const float* Wqk  = (const float*)d_in[5];
  const float* Wv   = (const float*)d_in[6];
  const float* Wo   = (const float*)d_in[7];
  const float* lfg  = (const float*)d_in[8];
  const float* lfb  = (const float*)d_in[9];
  const float* W1   = (const float*)d_in[10];
  const float* b1   = (const float*)d_in[11];
  const float* W2   = (const float*)d_in[12];
  const float* b2   = (const float*)d_in[13];
  const float* lnfg = (const float*)d_in[14];
  const float* lnfb = (const float*)d_in[15];
  const float* Wfc  = (const float*)d_in[16];
  const float* rot  = (const float*)d_in[17];

  char* ws = (char*)d_ws;
  size_t off = 0;
  auto carve = [&](size_t bytes) -> void* {
    void* p = ws + off;
    off += (bytes + 255) & ~(size_t)255;
    return p;
  };
  float* x1    = (float*)carve((size_t)ROWS_ * D_ * 4);
  float* x2    = (float*)carve((size_t)ROWS_ * D_ * 4);
  float* xn    = (float*)carve((size_t)ROWS_ * D_ * 4);
  float* qkb   = (float*)carve((size_t)ROWS_ * D_ * 4);
  __hip_bfloat16* vvb   = (__hip_bfloat16*)carve((size_t)ROWS_ * D_ * 2);
  __hip_bfloat16* qsb   = (__hip_bfloat16*)carve((size_t)ROWS_ * D_ * 2);
  __hip_bfloat16* knb   = (__hip_bfloat16*)carve((size_t)ROWS_ * D_ * 2);
  __hip_bfloat16* xnb   = (__hip_bfloat16*)carve((size_t)ROWS_ * D_ * 2);
  __hip_bfloat16* xnlo  = (__hip_bfloat16*)carve((size_t)ROWS_ * D_ * 2);
  __hip_bfloat16* attnb = (__hip_bfloat16*)carve((size_t)ROWS_ * D_ * 2);
  __hip_bfloat16* ob    = (__hip_bfloat16*)carve((size_t)BH_ * NH_ * T_ * DH_ * 2);  // 67 MB
  __hip_bfloat16* hid   = ob;  // alias: ob dead after combine; hid needs 32 MB
  unsigned char* bkt = (unsigned char*)carve((size_t)BH_ * NH_ * T_);
  int*   stb   = (int*)carve((size_t)BH_ * NH_ * T_ * 4);
  int*   undo  = (int*)carve((size_t)BH_ * NH_ * T_ * 4);
  float* lgb   = (float*)carve((size_t)BH_ * NH_ * T_ * 4);
  float* meanb = (float*)carve((size_t)B_ * D_ * 4);
  __hip_bfloat16* WvT  = (__hip_bfloat16*)carve((size_t)DEPTH_ * D_ * D_ * 2);
  __hip_bfloat16* WoT  = (__hip_bfloat16*)carve((size_t)DEPTH_ * D_ * D_ * 2);
  __hip_bfloat16* W1T  = (__hip_bfloat16*)carve((size_t)DEPTH_ * D_ * FF_ * 2);
  __hip_bfloat16* W2T  = (__hip_bfloat16*)carve((size_t)DEPTH_ * FF_ * D_ * 2);
  __hip_bfloat16* WqhT = (__hip_bfloat16*)carve((size_t)DEPTH_ * D_ * D_ * 2);
  __hip_bfloat16* WqlT = (__hip_bfloat16*)carve((size_t)DEPTH_ * D_ * D_ * 2);

  k_wt<<<dim3(D_ / 32, D_ / 32, DEPTH_), 256, 0, stream>>>(Wv, WvT, D_, D_);
  k_wt<<<dim3(D_ / 32, D_ / 32, DEPTH_), 256, 0, stream>>>(Wo, WoT, D_, D_);
  k_wt<<<dim3(FF_ / 32, D_ / 32, DEPTH_), 256, 0, stream>>>(W1, W1T, D_, FF_);
  k_wt<<<dim3(D_ / 32, FF_ / 32, DEPTH_), 256, 0, stream>>>(W2, W2T, FF_, D_);
  k_wt2<<<dim3(D_ / 32, D_ / 32, DEPTH_), 256, 0, stream>>>(Wqk, WqhT, WqlT, D_, D_);

  k_embed<<<ROWS_, 128, 0, stream>>>(ids, te, pe, x1, x2);

  for (int l = 0; l < DEPTH_; ++l) {
    const __hip_bfloat16* wvt = WvT + (size_t)l * D_ * D_;
    const __hip_bfloat16* wot = WoT + (size_t)l * D_ * D_;
    const __hip_bfloat16* w1t = W1T + (size_t)l * D_ * FF_;
    const __hip_bfloat16* w2t = W2T + (size_t)l * FF_ * D_;
    const __hip_bfloat16* wqh = WqhT + (size_t)l * D_ * D_;
    const __hip_bfloat16* wql = WqlT + (size_t)l * D_ * D_;

    k_ln<<<ROWS_ / 4, 256, 0, stream>>>(x2, nullptr, lag + l * D_, lab + l * D_, nullptr, xnb, xnlo);
    k_qgemm<<<dim3(D_ / 128, ROWS_ / 128), 256, 0, stream>>>(xnb, xnlo, wqh, wql, qkb, D_, D_);
    k_bgemm<4><<<dim3(D_ / 128, ROWS_ / 128), 256, 0, stream>>>(xnb, wvt, nullptr, vvb, D_, D_);
    k_prep<<<ROWS_ / 4, 256, 0, stream>>>(qkb, qsb, knb);
    k_bucket<<<512, 128, 0, stream>>>(qkb, rot + (size_t)l * 4096, bkt);
    k_sort<<<512, 1024, 0, stream>>>(bkt, stb, undo);
    k_attn<<<dim3(NC_, BH_), 256, 0, stream>>>(qsb, knb, vvb, stb, ob, lgb);
    k_combine<<<BH_ * T_ / 4, 256, 0, stream>>>(ob, lgb, undo, attnb);
    k_bgemm<1><<<dim3(D_ / 128, ROWS_ / 128), 256, 0, stream>>>(attnb, wot, nullptr, x1, D_, D_);

    k_ln<<<ROWS_ / 4, 256, 0, stream>>>(x1, nullptr, lfg + l * D_, lfb + l * D_, nullptr, xnb, nullptr);
    k_bgemm<2><<<dim3(FF_ / 128, ROWS_ / 128), 256, 0, stream>>>(xnb, w1t, b1 + l * FF_, hid, FF_, D_);
    k_bgemm<3><<<dim3(D_ / 128, ROWS_ / 128), 256, 0, stream>>>(hid, w2t, b2 + l * D_, x2, D_, FF_);
  }

  k_ln<<<ROWS_ / 4, 256, 0, stream>>>(x1, x2, lnfg, lnfb, xn, nullptr, nullptr);
  k_zero<<<16, 256, 0, stream>>>(meanb, B_ * D_);
  k_colsum<<<dim3(B_, 2, 16), 256, 0, stream>>>(xn, meanb);
  k_fc<<<B_, 512, 0, stream>>>(meanb, Wfc, (float*)d_out);
}